// Round 1
// baseline (1023.315 us; speedup 1.0000x reference)
//
#include <hip/hip_runtime.h>
#include <math.h>

#define NN 50000
#define NE 800000

// ---------------- init ----------------
__global__ void init_kernel(float* deg1, float* deg2, int* counts, int n) {
    int i = blockIdx.x * blockDim.x + threadIdx.x;
    if (i < n) { deg1[i] = 1.f; deg2[i] = 1.f; counts[i] = 0; }
}

// ---------------- geo dots ----------------
__global__ void geo_dot(const float* __restrict__ coords, const float* __restrict__ Wg,
                        float* __restrict__ geo_s, float* __restrict__ geo_d, int n) {
    int i = blockIdx.x * blockDim.x + threadIdx.x;
    if (i >= n) return;
    float4 c = *reinterpret_cast<const float4*>(coords + (size_t)i * 4);
    geo_s[i] = c.x * Wg[0] + c.y * Wg[1] + c.z * Wg[2] + c.w * Wg[3];
    geo_d[i] = c.x * Wg[4] + c.y * Wg[5] + c.z * Wg[6] + c.w * Wg[7];
}

// ---------------- dual dot: outs[n]=X[n]·W[0:C], outd[n]=X[n]·W[C:2C] ----------------
template <int C>
__global__ void dual_dot(const float* __restrict__ X, const float* __restrict__ W,
                         float* __restrict__ outs, float* __restrict__ outd, int n) {
    constexpr int V = C / 64;
    int lane = threadIdx.x & 63, wid = threadIdx.x >> 6;
    int node = blockIdx.x * (blockDim.x >> 6) + wid;
    if (node >= n) return;
    const float* xr = X + (size_t)node * C + lane * V;
    const float* ws = W + lane * V;
    const float* wd = W + C + lane * V;
    float ss = 0.f, dd = 0.f;
#pragma unroll
    for (int v = 0; v < V; v += 4) {
        float4 xv = *reinterpret_cast<const float4*>(xr + v);
        float4 a  = *reinterpret_cast<const float4*>(ws + v);
        float4 b  = *reinterpret_cast<const float4*>(wd + v);
        ss += xv.x * a.x + xv.y * a.y + xv.z * a.z + xv.w * a.w;
        dd += xv.x * b.x + xv.y * b.y + xv.z * b.z + xv.w * b.w;
    }
#pragma unroll
    for (int off = 32; off > 0; off >>= 1) {
        ss += __shfl_down(ss, off, 64);
        dd += __shfl_down(dd, off, 64);
    }
    if (lane == 0) { outs[node] = ss; outd[node] = dd; }
}

// ---------------- edge phase 1: edge_emb + deg1 + counts ----------------
__global__ void edge_phase1(const int* __restrict__ src, const int* __restrict__ dst,
                            const float* __restrict__ app_s, const float* __restrict__ app_d,
                            const float* __restrict__ geo_s, const float* __restrict__ geo_d,
                            const float* __restrict__ b_app, const float* __restrict__ b_geom,
                            const float* __restrict__ W_aff, const float* __restrict__ b_aff,
                            float* __restrict__ ew, float* __restrict__ deg1,
                            int* __restrict__ counts, int E) {
    int e = blockIdx.x * blockDim.x + threadIdx.x;
    if (e >= E) return;
    int s = src[e], d = dst[e];
    float x1 = fmaxf(app_s[s] + app_d[d] + b_app[0], 0.f);
    float x2 = fmaxf(geo_s[s] + geo_d[d] + b_geom[0], 0.f);
    float w = fmaxf(x1 * W_aff[0] + x2 * W_aff[1] + b_aff[0], 0.f);
    ew[e] = w;
    atomicAdd(&deg1[d], w);
    atomicAdd(&counts[d], 1);
}

// ---------------- edge phase 2: edge_attr2 + deg2 ----------------
__global__ void edge_phase2(const int* __restrict__ src, const int* __restrict__ dst,
                            const float* __restrict__ m_s, const float* __restrict__ m_d,
                            const float* __restrict__ b_m1,
                            float* __restrict__ ew2, float* __restrict__ deg2, int E) {
    int e = blockIdx.x * blockDim.x + threadIdx.x;
    if (e >= E) return;
    int s = src[e], d = dst[e];
    float w = fmaxf(m_s[s] + m_d[d] + b_m1[0], 0.f);
    ew2[e] = w;
    atomicAdd(&deg2[d], w);
}

// ---------------- dinv ----------------
__global__ void rsqrt_kernel(const float* __restrict__ deg, float* __restrict__ dinv, int n) {
    int i = blockIdx.x * blockDim.x + threadIdx.x;
    if (i >= n) return;
    float dg = deg[i];
    dinv[i] = dg > 0.f ? rsqrtf(fmaxf(dg, 1e-12f)) : 0.f;
}

// ---------------- single-block exclusive scan (n=50000) ----------------
__global__ __launch_bounds__(1024) void scan_kernel(const int* __restrict__ counts,
                                                    int* __restrict__ offsets,
                                                    int* __restrict__ cursor, int n) {
    __shared__ int wsum[16];
    __shared__ int carry_sh;
    int tid = threadIdx.x, lane = tid & 63, wid = tid >> 6;
    int running = 0;
    for (int base = 0; base < n; base += 4096) {
        int i0 = base + tid * 4;
        int4 v;
        if (i0 + 3 < n) v = *reinterpret_cast<const int4*>(counts + i0);
        else {
            v.x = (i0 + 0 < n) ? counts[i0 + 0] : 0;
            v.y = (i0 + 1 < n) ? counts[i0 + 1] : 0;
            v.z = (i0 + 2 < n) ? counts[i0 + 2] : 0;
            v.w = (i0 + 3 < n) ? counts[i0 + 3] : 0;
        }
        int tot = v.x + v.y + v.z + v.w;
        int inc = tot;
#pragma unroll
        for (int off = 1; off < 64; off <<= 1) {
            int t = __shfl_up(inc, off, 64);
            if (lane >= off) inc += t;
        }
        if (lane == 63) wsum[wid] = inc;
        __syncthreads();
        if (tid == 0) {
            int s = 0;
#pragma unroll
            for (int w = 0; w < 16; ++w) { int t = wsum[w]; wsum[w] = s; s += t; }
            carry_sh = s;
        }
        __syncthreads();
        int ex = running + wsum[wid] + (inc - tot);
        int4 o;
        o.x = ex; o.y = ex + v.x; o.z = ex + v.x + v.y; o.w = ex + v.x + v.y + v.z;
        if (i0 + 3 < n) {
            *reinterpret_cast<int4*>(offsets + i0) = o;
            *reinterpret_cast<int4*>(cursor + i0) = o;
        } else {
            if (i0 + 0 < n) { offsets[i0 + 0] = o.x; cursor[i0 + 0] = o.x; }
            if (i0 + 1 < n) { offsets[i0 + 1] = o.y; cursor[i0 + 1] = o.y; }
            if (i0 + 2 < n) { offsets[i0 + 2] = o.z; cursor[i0 + 2] = o.z; }
            if (i0 + 3 < n) { offsets[i0 + 3] = o.w; cursor[i0 + 3] = o.w; }
        }
        running += carry_sh;
        __syncthreads();
    }
    if (tid == 0) offsets[n] = running;
}

// ---------------- CSR scatter ----------------
__global__ void scatter_kernel(const int* __restrict__ dst, int* __restrict__ cursor,
                               int* __restrict__ eid, int E) {
    int e = blockIdx.x * blockDim.x + threadIdx.x;
    if (e >= E) return;
    int pos = atomicAdd(&cursor[dst[e]], 1);
    eid[pos] = e;
}

// ---------------- f32 tiled GEMM: C[M,N] = A[M,K] * B[K,N] ----------------
__global__ __launch_bounds__(256) void gemm64(const float* __restrict__ A,
                                              const float* __restrict__ B,
                                              float* __restrict__ C, int M, int N, int K) {
    __shared__ float As[16][64];  // [k][m]
    __shared__ float Bs[16][64];  // [k][n]
    int tid = threadIdx.x;
    int row0 = blockIdx.x * 64;
    int col0 = blockIdx.y * 64;
    int ty = tid >> 4, tx = tid & 15;
    int lm = tid >> 2, lk = (tid & 3) << 2;
    int bk = tid >> 4, bc = (tid & 15) << 2;
    float acc[4][4] = {{0.f}};
    for (int k0 = 0; k0 < K; k0 += 16) {
        float4 av;
        int ar = row0 + lm;
        if (ar < M) av = *reinterpret_cast<const float4*>(A + (size_t)ar * K + k0 + lk);
        else av = make_float4(0.f, 0.f, 0.f, 0.f);
        As[lk + 0][lm] = av.x; As[lk + 1][lm] = av.y;
        As[lk + 2][lm] = av.z; As[lk + 3][lm] = av.w;
        *reinterpret_cast<float4*>(&Bs[bk][bc]) =
            *reinterpret_cast<const float4*>(B + (size_t)(k0 + bk) * N + col0 + bc);
        __syncthreads();
#pragma unroll
        for (int k = 0; k < 16; ++k) {
            float4 a4 = *reinterpret_cast<const float4*>(&As[k][ty << 2]);
            float4 b4 = *reinterpret_cast<const float4*>(&Bs[k][tx << 2]);
            acc[0][0] += a4.x * b4.x; acc[0][1] += a4.x * b4.y; acc[0][2] += a4.x * b4.z; acc[0][3] += a4.x * b4.w;
            acc[1][0] += a4.y * b4.x; acc[1][1] += a4.y * b4.y; acc[1][2] += a4.y * b4.z; acc[1][3] += a4.y * b4.w;
            acc[2][0] += a4.z * b4.x; acc[2][1] += a4.z * b4.y; acc[2][2] += a4.z * b4.z; acc[2][3] += a4.z * b4.w;
            acc[3][0] += a4.w * b4.x; acc[3][1] += a4.w * b4.y; acc[3][2] += a4.w * b4.z; acc[3][3] += a4.w * b4.w;
        }
        __syncthreads();
    }
#pragma unroll
    for (int i = 0; i < 4; ++i) {
        int r = row0 + (ty << 2) + i;
        if (r < M) {
            float4 o = make_float4(acc[i][0], acc[i][1], acc[i][2], acc[i][3]);
            *reinterpret_cast<float4*>(C + (size_t)r * N + col0 + (tx << 2)) = o;
        }
    }
}

// ---------------- GCN aggregation: wave per node, CSR gather ----------------
template <int C, bool RELU>
__global__ void conv_agg(const float* __restrict__ h, const float* __restrict__ dinv,
                         const float* __restrict__ ew, const int* __restrict__ src,
                         const int* __restrict__ offsets, const int* __restrict__ eid,
                         const float* __restrict__ bias, float* __restrict__ out, int n) {
    constexpr int V = C / 64;
    int lane = threadIdx.x & 63, wid = threadIdx.x >> 6;
    int node = blockIdx.x * (blockDim.x >> 6) + wid;
    if (node >= n) return;
    float dn = dinv[node];
    float acc[V];
    {
        const float* hn = h + (size_t)node * C + lane * V;
        float sw = dn * dn;
        if constexpr (V == 4) {
            float4 v = *reinterpret_cast<const float4*>(hn);
            acc[0] = sw * v.x; acc[1] = sw * v.y; acc[2] = sw * v.z; acc[3] = sw * v.w;
        } else {
            float2 v = *reinterpret_cast<const float2*>(hn);
            acc[0] = sw * v.x; acc[1] = sw * v.y;
        }
    }
    int j0 = offsets[node], j1 = offsets[node + 1];
    for (int j = j0; j < j1; ++j) {
        int e = eid[j];
        int s = src[e];
        float nrm = dinv[s] * ew[e] * dn;
        const float* hs = h + (size_t)s * C + lane * V;
        if constexpr (V == 4) {
            float4 v = *reinterpret_cast<const float4*>(hs);
            acc[0] += nrm * v.x; acc[1] += nrm * v.y; acc[2] += nrm * v.z; acc[3] += nrm * v.w;
        } else {
            float2 v = *reinterpret_cast<const float2*>(hs);
            acc[0] += nrm * v.x; acc[1] += nrm * v.y;
        }
    }
    const float* bp = bias + lane * V;
    float* op = out + (size_t)node * C + lane * V;
    if constexpr (V == 4) {
        float4 o;
        o.x = acc[0] + bp[0]; o.y = acc[1] + bp[1]; o.z = acc[2] + bp[2]; o.w = acc[3] + bp[3];
        if (RELU) { o.x = fmaxf(o.x, 0.f); o.y = fmaxf(o.y, 0.f); o.z = fmaxf(o.z, 0.f); o.w = fmaxf(o.w, 0.f); }
        *reinterpret_cast<float4*>(op) = o;
    } else {
        float2 o;
        o.x = acc[0] + bp[0]; o.y = acc[1] + bp[1];
        if (RELU) { o.x = fmaxf(o.x, 0.f); o.y = fmaxf(o.y, 0.f); }
        *reinterpret_cast<float2*>(op) = o;
    }
}

// ---------------- fused pairwise classifier ----------------
__global__ __launch_bounds__(256) void final_mlp(const float* __restrict__ out2,
                                                 const int* __restrict__ ea,
                                                 const int* __restrict__ eb,
                                                 const float* __restrict__ W_f1,
                                                 const float* __restrict__ b_f1,
                                                 const float* __restrict__ W_f2,
                                                 const float* __restrict__ b_f2,
                                                 float* __restrict__ out) {
    __shared__ float dT[128][64];     // diff transposed [k][edge]
    __shared__ float Bs[128 * 64];    // W_f1 [k][l]
    int tid = threadIdx.x;
    {
        const float4* wsrc = reinterpret_cast<const float4*>(W_f1);
        float4* bdst = reinterpret_cast<float4*>(Bs);
#pragma unroll
        for (int i = 0; i < 8; ++i) bdst[tid + 256 * i] = wsrc[tid + 256 * i];
    }
    int e0 = blockIdx.x * 64;
    {
        int m = tid >> 2, q = tid & 3;
        int e = e0 + m;
        int a = ea[e], b = eb[e];
        const float4* pa = reinterpret_cast<const float4*>(out2 + (size_t)a * 128 + q * 32);
        const float4* pb = reinterpret_cast<const float4*>(out2 + (size_t)b * 128 + q * 32);
#pragma unroll
        for (int r = 0; r < 8; ++r) {
            float4 va = pa[r], vb = pb[r];
            int k = q * 32 + r * 4;
            dT[k + 0][m] = va.x - vb.x;
            dT[k + 1][m] = va.y - vb.y;
            dT[k + 2][m] = va.z - vb.z;
            dT[k + 3][m] = va.w - vb.w;
        }
    }
    __syncthreads();
    int ty = tid >> 4, tx = tid & 15;
    float acc[4][4] = {{0.f}};
#pragma unroll 8
    for (int k = 0; k < 128; ++k) {
        float4 a4 = *reinterpret_cast<const float4*>(&dT[k][ty << 2]);
        float4 b4 = *reinterpret_cast<const float4*>(&Bs[k * 64 + (tx << 2)]);
        acc[0][0] += a4.x * b4.x; acc[0][1] += a4.x * b4.y; acc[0][2] += a4.x * b4.z; acc[0][3] += a4.x * b4.w;
        acc[1][0] += a4.y * b4.x; acc[1][1] += a4.y * b4.y; acc[1][2] += a4.y * b4.z; acc[1][3] += a4.y * b4.w;
        acc[2][0] += a4.z * b4.x; acc[2][1] += a4.z * b4.y; acc[2][2] += a4.z * b4.z; acc[2][3] += a4.z * b4.w;
        acc[3][0] += a4.w * b4.x; acc[3][1] += a4.w * b4.y; acc[3][2] += a4.w * b4.z; acc[3][3] += a4.w * b4.w;
    }
    float wf2[4], bf1[4];
#pragma unroll
    for (int j = 0; j < 4; ++j) {
        wf2[j] = W_f2[(tx << 2) + j];
        bf1[j] = b_f1[(tx << 2) + j];
    }
    float bb = b_f2[0];
#pragma unroll
    for (int i = 0; i < 4; ++i) {
        float p = 0.f;
#pragma unroll
        for (int j = 0; j < 4; ++j) p += fmaxf(acc[i][j] + bf1[j], 0.f) * wf2[j];
        p += __shfl_xor(p, 8, 64);
        p += __shfl_xor(p, 4, 64);
        p += __shfl_xor(p, 2, 64);
        p += __shfl_xor(p, 1, 64);
        if (tx == 0) out[e0 + (ty << 2) + i] = 1.f / (1.f + expf(-(p + bb)));
    }
}

extern "C" void kernel_launch(void* const* d_in, const int* in_sizes, int n_in,
                              void* d_out, int out_size, void* d_ws, size_t ws_size,
                              hipStream_t stream) {
    const float* x      = (const float*)d_in[0];
    const float* coords = (const float*)d_in[1];
    const float* W_app  = (const float*)d_in[2];
    const float* b_app  = (const float*)d_in[3];
    const float* W_geom = (const float*)d_in[4];
    const float* b_geom = (const float*)d_in[5];
    const float* W_aff  = (const float*)d_in[6];
    const float* b_aff  = (const float*)d_in[7];
    const float* W_c1   = (const float*)d_in[8];
    const float* b_c1   = (const float*)d_in[9];
    const float* W_m1   = (const float*)d_in[10];
    const float* b_m1   = (const float*)d_in[11];
    const float* W_c2   = (const float*)d_in[12];
    const float* b_c2   = (const float*)d_in[13];
    const float* W_f1   = (const float*)d_in[14];
    const float* b_f1   = (const float*)d_in[15];
    const float* W_f2   = (const float*)d_in[16];
    const float* b_f2   = (const float*)d_in[17];
    const int*   e1     = (const int*)d_in[18];
    const int*   e2     = (const int*)d_in[19];
    float* out = (float*)d_out;

    const int N = NN;
    const int E = NE;
    const int* src1 = e1;
    const int* dst1 = e1 + E;
    const int* e2a = e2;
    const int* e2b = e2 + E;

    char* ws = (char*)d_ws;
    size_t off = 0;
    auto alloc = [&](size_t bytes) -> void* {
        void* p = ws + off;
        off += (bytes + 255) & ~(size_t)255;
        return p;
    };
    float* app_s = (float*)alloc((size_t)N * 4);
    float* app_d = (float*)alloc((size_t)N * 4);
    float* geo_s = (float*)alloc((size_t)N * 4);
    float* geo_d = (float*)alloc((size_t)N * 4);
    float* m_s   = (float*)alloc((size_t)N * 4);
    float* m_d   = (float*)alloc((size_t)N * 4);
    float* deg1  = (float*)alloc((size_t)N * 4);
    float* dinv1 = (float*)alloc((size_t)N * 4);
    float* deg2  = (float*)alloc((size_t)N * 4);
    float* dinv2 = (float*)alloc((size_t)N * 4);
    int* counts  = (int*)alloc((size_t)N * 4);
    int* offsets = (int*)alloc((size_t)(N + 1) * 4);
    int* cursor  = (int*)alloc((size_t)N * 4);
    int* eid     = (int*)alloc((size_t)E * 4);
    float* ew    = (float*)alloc((size_t)E * 4);
    float* ew2   = (float*)alloc((size_t)E * 4);
    float* h     = (float*)alloc((size_t)N * 256 * 4);
    float* out1  = (float*)alloc((size_t)N * 256 * 4);
    // h dead after conv1 aggregation -> reuse its region
    float* h2   = h;
    float* out2 = h + (size_t)N * 128;

    int gN = (N + 255) / 256;
    int gE = (E + 255) / 256;
    int gW = (N + 3) / 4;  // wave-per-node kernels, 4 waves/block

    init_kernel<<<gN, 256, 0, stream>>>(deg1, deg2, counts, N);
    geo_dot<<<gN, 256, 0, stream>>>(coords, W_geom, geo_s, geo_d, N);
    dual_dot<512><<<gW, 256, 0, stream>>>(x, W_app, app_s, app_d, N);
    edge_phase1<<<gE, 256, 0, stream>>>(src1, dst1, app_s, app_d, geo_s, geo_d,
                                        b_app, b_geom, W_aff, b_aff, ew, deg1, counts, E);
    rsqrt_kernel<<<gN, 256, 0, stream>>>(deg1, dinv1, N);
    scan_kernel<<<1, 1024, 0, stream>>>(counts, offsets, cursor, N);
    scatter_kernel<<<gE, 256, 0, stream>>>(dst1, cursor, eid, E);

    // h = x @ W_c1  [N,512]x[512,256]
    gemm64<<<dim3((N + 63) / 64, 256 / 64), 256, 0, stream>>>(x, W_c1, h, N, 256, 512);
    // out1 = relu(agg(h) + b_c1)
    conv_agg<256, true><<<gW, 256, 0, stream>>>(h, dinv1, ew, src1, offsets, eid, b_c1, out1, N);

    // m_s/m_d from out1, edge_attr2, deg2
    dual_dot<256><<<gW, 256, 0, stream>>>(out1, W_m1, m_s, m_d, N);
    edge_phase2<<<gE, 256, 0, stream>>>(src1, dst1, m_s, m_d, b_m1, ew2, deg2, E);
    rsqrt_kernel<<<gN, 256, 0, stream>>>(deg2, dinv2, N);

    // h2 = out1 @ W_c2  [N,256]x[256,128]
    gemm64<<<dim3((N + 63) / 64, 128 / 64), 256, 0, stream>>>(out1, W_c2, h2, N, 128, 256);
    // out2 = agg(h2) + b_c2 (no relu)
    conv_agg<128, false><<<gW, 256, 0, stream>>>(h2, dinv2, ew2, src1, offsets, eid, b_c2, out2, N);

    // final pairwise classifier on edge_index2
    final_mlp<<<E / 64, 256, 0, stream>>>(out2, e2a, e2b, W_f1, b_f1, W_f2, b_f2, out);
}

// Round 2
// 785.677 us; speedup vs baseline: 1.3025x; 1.3025x over previous
//
#include <hip/hip_runtime.h>
#include <math.h>

#define NN 50000
#define NE 800000

// ---------------- init ----------------
__global__ void init_kernel(float* deg1, float* deg2, int* counts, int n) {
    int i = blockIdx.x * blockDim.x + threadIdx.x;
    if (i < n) { deg1[i] = 1.f; deg2[i] = 1.f; counts[i] = 0; }
}

// ---------------- geo dots ----------------
__global__ void geo_dot(const float* __restrict__ coords, const float* __restrict__ Wg,
                        float* __restrict__ geo_s, float* __restrict__ geo_d, int n) {
    int i = blockIdx.x * blockDim.x + threadIdx.x;
    if (i >= n) return;
    float4 c = *reinterpret_cast<const float4*>(coords + (size_t)i * 4);
    geo_s[i] = c.x * Wg[0] + c.y * Wg[1] + c.z * Wg[2] + c.w * Wg[3];
    geo_d[i] = c.x * Wg[4] + c.y * Wg[5] + c.z * Wg[6] + c.w * Wg[7];
}

// ---------------- dual dot: outs[n]=X[n]·W[0:C], outd[n]=X[n]·W[C:2C] ----------------
template <int C>
__global__ void dual_dot(const float* __restrict__ X, const float* __restrict__ W,
                         float* __restrict__ outs, float* __restrict__ outd, int n) {
    constexpr int V = C / 64;
    int lane = threadIdx.x & 63, wid = threadIdx.x >> 6;
    int node = blockIdx.x * (blockDim.x >> 6) + wid;
    if (node >= n) return;
    const float* xr = X + (size_t)node * C + lane * V;
    const float* ws = W + lane * V;
    const float* wd = W + C + lane * V;
    float ss = 0.f, dd = 0.f;
#pragma unroll
    for (int v = 0; v < V; v += 4) {
        float4 xv = *reinterpret_cast<const float4*>(xr + v);
        float4 a  = *reinterpret_cast<const float4*>(ws + v);
        float4 b  = *reinterpret_cast<const float4*>(wd + v);
        ss += xv.x * a.x + xv.y * a.y + xv.z * a.z + xv.w * a.w;
        dd += xv.x * b.x + xv.y * b.y + xv.z * b.z + xv.w * b.w;
    }
#pragma unroll
    for (int off = 32; off > 0; off >>= 1) {
        ss += __shfl_down(ss, off, 64);
        dd += __shfl_down(dd, off, 64);
    }
    if (lane == 0) { outs[node] = ss; outd[node] = dd; }
}

// ---------------- edge phase 1: edge_emb + deg1 + counts ----------------
__global__ void edge_phase1(const int* __restrict__ src, const int* __restrict__ dst,
                            const float* __restrict__ app_s, const float* __restrict__ app_d,
                            const float* __restrict__ geo_s, const float* __restrict__ geo_d,
                            const float* __restrict__ b_app, const float* __restrict__ b_geom,
                            const float* __restrict__ W_aff, const float* __restrict__ b_aff,
                            float* __restrict__ ew, float* __restrict__ deg1,
                            int* __restrict__ counts, int E) {
    int e = blockIdx.x * blockDim.x + threadIdx.x;
    if (e >= E) return;
    int s = src[e], d = dst[e];
    float x1 = fmaxf(app_s[s] + app_d[d] + b_app[0], 0.f);
    float x2 = fmaxf(geo_s[s] + geo_d[d] + b_geom[0], 0.f);
    float w = fmaxf(x1 * W_aff[0] + x2 * W_aff[1] + b_aff[0], 0.f);
    ew[e] = w;
    atomicAdd(&deg1[d], w);
    atomicAdd(&counts[d], 1);
}

// ---------------- edge phase 2: edge_attr2 + deg2 ----------------
__global__ void edge_phase2(const int* __restrict__ src, const int* __restrict__ dst,
                            const float* __restrict__ m_s, const float* __restrict__ m_d,
                            const float* __restrict__ b_m1,
                            float* __restrict__ ew2, float* __restrict__ deg2, int E) {
    int e = blockIdx.x * blockDim.x + threadIdx.x;
    if (e >= E) return;
    int s = src[e], d = dst[e];
    float w = fmaxf(m_s[s] + m_d[d] + b_m1[0], 0.f);
    ew2[e] = w;
    atomicAdd(&deg2[d], w);
}

// ---------------- dinv ----------------
__global__ void rsqrt_kernel(const float* __restrict__ deg, float* __restrict__ dinv, int n) {
    int i = blockIdx.x * blockDim.x + threadIdx.x;
    if (i >= n) return;
    float dg = deg[i];
    dinv[i] = dg > 0.f ? rsqrtf(fmaxf(dg, 1e-12f)) : 0.f;
}

// ---------------- single-block exclusive scan (n=50000) ----------------
__global__ __launch_bounds__(1024) void scan_kernel(const int* __restrict__ counts,
                                                    int* __restrict__ offsets,
                                                    int* __restrict__ cursor, int n) {
    __shared__ int wsum[16];
    __shared__ int carry_sh;
    int tid = threadIdx.x, lane = tid & 63, wid = tid >> 6;
    int running = 0;
    for (int base = 0; base < n; base += 4096) {
        int i0 = base + tid * 4;
        int4 v;
        if (i0 + 3 < n) v = *reinterpret_cast<const int4*>(counts + i0);
        else {
            v.x = (i0 + 0 < n) ? counts[i0 + 0] : 0;
            v.y = (i0 + 1 < n) ? counts[i0 + 1] : 0;
            v.z = (i0 + 2 < n) ? counts[i0 + 2] : 0;
            v.w = (i0 + 3 < n) ? counts[i0 + 3] : 0;
        }
        int tot = v.x + v.y + v.z + v.w;
        int inc = tot;
#pragma unroll
        for (int off = 1; off < 64; off <<= 1) {
            int t = __shfl_up(inc, off, 64);
            if (lane >= off) inc += t;
        }
        if (lane == 63) wsum[wid] = inc;
        __syncthreads();
        if (tid == 0) {
            int s = 0;
#pragma unroll
            for (int w = 0; w < 16; ++w) { int t = wsum[w]; wsum[w] = s; s += t; }
            carry_sh = s;
        }
        __syncthreads();
        int ex = running + wsum[wid] + (inc - tot);
        int4 o;
        o.x = ex; o.y = ex + v.x; o.z = ex + v.x + v.y; o.w = ex + v.x + v.y + v.z;
        if (i0 + 3 < n) {
            *reinterpret_cast<int4*>(offsets + i0) = o;
            *reinterpret_cast<int4*>(cursor + i0) = o;
        } else {
            if (i0 + 0 < n) { offsets[i0 + 0] = o.x; cursor[i0 + 0] = o.x; }
            if (i0 + 1 < n) { offsets[i0 + 1] = o.y; cursor[i0 + 1] = o.y; }
            if (i0 + 2 < n) { offsets[i0 + 2] = o.z; cursor[i0 + 2] = o.z; }
            if (i0 + 3 < n) { offsets[i0 + 3] = o.w; cursor[i0 + 3] = o.w; }
        }
        running += carry_sh;
        __syncthreads();
    }
    if (tid == 0) offsets[n] = running;
}

// ---------------- CSR scatter ----------------
__global__ void scatter_kernel(const int* __restrict__ dst, int* __restrict__ cursor,
                               int* __restrict__ eid, int E) {
    int e = blockIdx.x * blockDim.x + threadIdx.x;
    if (e >= E) return;
    int pos = atomicAdd(&cursor[dst[e]], 1);
    eid[pos] = e;
}

// ---------------- build per-slot CSR coefficient streams ----------------
// csr_src[j] = src[eid[j]]; csr_a[j] = dinv[src]*ew[eid[j]]
__global__ void build_csr1(const int* __restrict__ eid, const int* __restrict__ src,
                           const float* __restrict__ dinv, const float* __restrict__ ew,
                           int* __restrict__ csr_src, float* __restrict__ csr_a, int E) {
    int j = blockIdx.x * blockDim.x + threadIdx.x;
    if (j >= E) return;
    int e = eid[j];
    int s = src[e];
    csr_src[j] = s;
    csr_a[j] = dinv[s] * ew[e];
}

// second conv: reuse csr_src, rebuild csr_a with new dinv/ew
__global__ void build_csr2(const int* __restrict__ eid, const int* __restrict__ csr_src,
                           const float* __restrict__ dinv, const float* __restrict__ ew,
                           float* __restrict__ csr_a, int E) {
    int j = blockIdx.x * blockDim.x + threadIdx.x;
    if (j >= E) return;
    csr_a[j] = dinv[csr_src[j]] * ew[eid[j]];
}

// ---------------- f32 tiled GEMM: C[M,N] = A[M,K] * B[K,N] ----------------
__global__ __launch_bounds__(256) void gemm64(const float* __restrict__ A,
                                              const float* __restrict__ B,
                                              float* __restrict__ C, int M, int N, int K) {
    __shared__ float As[16][64];  // [k][m]
    __shared__ float Bs[16][64];  // [k][n]
    int tid = threadIdx.x;
    int row0 = blockIdx.x * 64;
    int col0 = blockIdx.y * 64;
    int ty = tid >> 4, tx = tid & 15;
    int lm = tid >> 2, lk = (tid & 3) << 2;
    int bk = tid >> 4, bc = (tid & 15) << 2;
    float acc[4][4] = {{0.f}};
    for (int k0 = 0; k0 < K; k0 += 16) {
        float4 av;
        int ar = row0 + lm;
        if (ar < M) av = *reinterpret_cast<const float4*>(A + (size_t)ar * K + k0 + lk);
        else av = make_float4(0.f, 0.f, 0.f, 0.f);
        As[lk + 0][lm] = av.x; As[lk + 1][lm] = av.y;
        As[lk + 2][lm] = av.z; As[lk + 3][lm] = av.w;
        *reinterpret_cast<float4*>(&Bs[bk][bc]) =
            *reinterpret_cast<const float4*>(B + (size_t)(k0 + bk) * N + col0 + bc);
        __syncthreads();
#pragma unroll
        for (int k = 0; k < 16; ++k) {
            float4 a4 = *reinterpret_cast<const float4*>(&As[k][ty << 2]);
            float4 b4 = *reinterpret_cast<const float4*>(&Bs[k][tx << 2]);
            acc[0][0] += a4.x * b4.x; acc[0][1] += a4.x * b4.y; acc[0][2] += a4.x * b4.z; acc[0][3] += a4.x * b4.w;
            acc[1][0] += a4.y * b4.x; acc[1][1] += a4.y * b4.y; acc[1][2] += a4.y * b4.z; acc[1][3] += a4.y * b4.w;
            acc[2][0] += a4.z * b4.x; acc[2][1] += a4.z * b4.y; acc[2][2] += a4.z * b4.z; acc[2][3] += a4.z * b4.w;
            acc[3][0] += a4.w * b4.x; acc[3][1] += a4.w * b4.y; acc[3][2] += a4.w * b4.z; acc[3][3] += a4.w * b4.w;
        }
        __syncthreads();
    }
#pragma unroll
    for (int i = 0; i < 4; ++i) {
        int r = row0 + (ty << 2) + i;
        if (r < M) {
            float4 o = make_float4(acc[i][0], acc[i][1], acc[i][2], acc[i][3]);
            *reinterpret_cast<float4*>(C + (size_t)r * N + col0 + (tx << 2)) = o;
        }
    }
}

// ---------------- GCN aggregation: wave per node, precomputed CSR streams ----------------
// out[node] = dinv[node] * (dinv[node]*h[node] + sum_j csr_a[j]*h[csr_src[j]]) + bias
template <int C, bool RELU>
__global__ void conv_agg(const float* __restrict__ h, const float* __restrict__ dinv,
                         const int* __restrict__ csr_src, const float* __restrict__ csr_a,
                         const int* __restrict__ offsets,
                         const float* __restrict__ bias, float* __restrict__ out, int n) {
    constexpr int V = C / 64;
    int lane = threadIdx.x & 63, wid = threadIdx.x >> 6;
    int node = blockIdx.x * (blockDim.x >> 6) + wid;
    if (node >= n) return;
    float dn = dinv[node];
    float acc[V];
    {
        const float* hn = h + (size_t)node * C + lane * V;
        if constexpr (V == 4) {
            float4 v = *reinterpret_cast<const float4*>(hn);
            acc[0] = dn * v.x; acc[1] = dn * v.y; acc[2] = dn * v.z; acc[3] = dn * v.w;
        } else {
            float2 v = *reinterpret_cast<const float2*>(hn);
            acc[0] = dn * v.x; acc[1] = dn * v.y;
        }
    }
    int j0 = offsets[node], j1 = offsets[node + 1];
    int j = j0;
    for (; j + 4 <= j1; j += 4) {
        int s0 = csr_src[j], s1 = csr_src[j + 1], s2 = csr_src[j + 2], s3 = csr_src[j + 3];
        float a0 = csr_a[j], a1 = csr_a[j + 1], a2 = csr_a[j + 2], a3 = csr_a[j + 3];
        if constexpr (V == 4) {
            float4 v0 = *reinterpret_cast<const float4*>(h + (size_t)s0 * C + lane * 4);
            float4 v1 = *reinterpret_cast<const float4*>(h + (size_t)s1 * C + lane * 4);
            float4 v2 = *reinterpret_cast<const float4*>(h + (size_t)s2 * C + lane * 4);
            float4 v3 = *reinterpret_cast<const float4*>(h + (size_t)s3 * C + lane * 4);
            acc[0] += a0 * v0.x + a1 * v1.x + a2 * v2.x + a3 * v3.x;
            acc[1] += a0 * v0.y + a1 * v1.y + a2 * v2.y + a3 * v3.y;
            acc[2] += a0 * v0.z + a1 * v1.z + a2 * v2.z + a3 * v3.z;
            acc[3] += a0 * v0.w + a1 * v1.w + a2 * v2.w + a3 * v3.w;
        } else {
            float2 v0 = *reinterpret_cast<const float2*>(h + (size_t)s0 * C + lane * 2);
            float2 v1 = *reinterpret_cast<const float2*>(h + (size_t)s1 * C + lane * 2);
            float2 v2 = *reinterpret_cast<const float2*>(h + (size_t)s2 * C + lane * 2);
            float2 v3 = *reinterpret_cast<const float2*>(h + (size_t)s3 * C + lane * 2);
            acc[0] += a0 * v0.x + a1 * v1.x + a2 * v2.x + a3 * v3.x;
            acc[1] += a0 * v0.y + a1 * v1.y + a2 * v2.y + a3 * v3.y;
        }
    }
    for (; j < j1; ++j) {
        int s = csr_src[j];
        float a = csr_a[j];
        const float* hs = h + (size_t)s * C + lane * V;
        if constexpr (V == 4) {
            float4 v = *reinterpret_cast<const float4*>(hs);
            acc[0] += a * v.x; acc[1] += a * v.y; acc[2] += a * v.z; acc[3] += a * v.w;
        } else {
            float2 v = *reinterpret_cast<const float2*>(hs);
            acc[0] += a * v.x; acc[1] += a * v.y;
        }
    }
    const float* bp = bias + lane * V;
    float* op = out + (size_t)node * C + lane * V;
    if constexpr (V == 4) {
        float4 o;
        o.x = acc[0] * dn + bp[0]; o.y = acc[1] * dn + bp[1];
        o.z = acc[2] * dn + bp[2]; o.w = acc[3] * dn + bp[3];
        if (RELU) { o.x = fmaxf(o.x, 0.f); o.y = fmaxf(o.y, 0.f); o.z = fmaxf(o.z, 0.f); o.w = fmaxf(o.w, 0.f); }
        *reinterpret_cast<float4*>(op) = o;
    } else {
        float2 o;
        o.x = acc[0] * dn + bp[0]; o.y = acc[1] * dn + bp[1];
        if (RELU) { o.x = fmaxf(o.x, 0.f); o.y = fmaxf(o.y, 0.f); }
        *reinterpret_cast<float2*>(op) = o;
    }
}

// ---------------- final pairwise classifier on precomputed y1 = out2 @ W_f1 ----------------
// out[e] = sigmoid(relu(y1[a]-y1[b]+b_f1) . W_f2 + b_f2)
// 16 lanes per edge, 4 edges per wave.
__global__ __launch_bounds__(256) void final_edge(const float* __restrict__ y1,
                                                  const int* __restrict__ ea,
                                                  const int* __restrict__ eb,
                                                  const float* __restrict__ b_f1,
                                                  const float* __restrict__ W_f2,
                                                  const float* __restrict__ b_f2,
                                                  float* __restrict__ out, int E) {
    int lane = threadIdx.x & 63, wid = threadIdx.x >> 6;
    int sub = lane >> 4, k4 = lane & 15;
    int wave = blockIdx.x * 4 + wid;
    int e = wave * 4 + sub;
    if (e >= E) return;
    float4 bf1 = *reinterpret_cast<const float4*>(b_f1 + k4 * 4);
    float4 wf2 = *reinterpret_cast<const float4*>(W_f2 + k4 * 4);
    int a = ea[e], b = eb[e];
    float4 va = *reinterpret_cast<const float4*>(y1 + (size_t)a * 64 + k4 * 4);
    float4 vb = *reinterpret_cast<const float4*>(y1 + (size_t)b * 64 + k4 * 4);
    float p = fmaxf(va.x - vb.x + bf1.x, 0.f) * wf2.x
            + fmaxf(va.y - vb.y + bf1.y, 0.f) * wf2.y
            + fmaxf(va.z - vb.z + bf1.z, 0.f) * wf2.z
            + fmaxf(va.w - vb.w + bf1.w, 0.f) * wf2.w;
    p += __shfl_xor(p, 1, 64);
    p += __shfl_xor(p, 2, 64);
    p += __shfl_xor(p, 4, 64);
    p += __shfl_xor(p, 8, 64);
    if (k4 == 0) out[e] = 1.f / (1.f + expf(-(p + b_f2[0])));
}

extern "C" void kernel_launch(void* const* d_in, const int* in_sizes, int n_in,
                              void* d_out, int out_size, void* d_ws, size_t ws_size,
                              hipStream_t stream) {
    const float* x      = (const float*)d_in[0];
    const float* coords = (const float*)d_in[1];
    const float* W_app  = (const float*)d_in[2];
    const float* b_app  = (const float*)d_in[3];
    const float* W_geom = (const float*)d_in[4];
    const float* b_geom = (const float*)d_in[5];
    const float* W_aff  = (const float*)d_in[6];
    const float* b_aff  = (const float*)d_in[7];
    const float* W_c1   = (const float*)d_in[8];
    const float* b_c1   = (const float*)d_in[9];
    const float* W_m1   = (const float*)d_in[10];
    const float* b_m1   = (const float*)d_in[11];
    const float* W_c2   = (const float*)d_in[12];
    const float* b_c2   = (const float*)d_in[13];
    const float* W_f1   = (const float*)d_in[14];
    const float* b_f1   = (const float*)d_in[15];
    const float* W_f2   = (const float*)d_in[16];
    const float* b_f2   = (const float*)d_in[17];
    const int*   e1     = (const int*)d_in[18];
    const int*   e2     = (const int*)d_in[19];
    float* out = (float*)d_out;

    const int N = NN;
    const int E = NE;
    const int* src1 = e1;
    const int* dst1 = e1 + E;
    const int* e2a = e2;
    const int* e2b = e2 + E;

    char* ws = (char*)d_ws;
    size_t off = 0;
    auto alloc = [&](size_t bytes) -> void* {
        void* p = ws + off;
        off += (bytes + 255) & ~(size_t)255;
        return p;
    };
    float* app_s = (float*)alloc((size_t)N * 4);
    float* app_d = (float*)alloc((size_t)N * 4);
    float* geo_s = (float*)alloc((size_t)N * 4);
    float* geo_d = (float*)alloc((size_t)N * 4);
    float* m_s   = (float*)alloc((size_t)N * 4);
    float* m_d   = (float*)alloc((size_t)N * 4);
    float* deg1  = (float*)alloc((size_t)N * 4);
    float* dinv1 = (float*)alloc((size_t)N * 4);
    float* deg2  = (float*)alloc((size_t)N * 4);
    float* dinv2 = (float*)alloc((size_t)N * 4);
    int* counts  = (int*)alloc((size_t)N * 4);
    int* offsets = (int*)alloc((size_t)(N + 1) * 4);
    int* cursor  = (int*)alloc((size_t)N * 4);
    int* eid     = (int*)alloc((size_t)E * 4);
    float* ew    = (float*)alloc((size_t)E * 4);
    float* ew2   = (float*)alloc((size_t)E * 4);
    int* csr_src = (int*)alloc((size_t)E * 4);
    float* csr_a = (float*)alloc((size_t)E * 4);  // rebuilt between conv1 and conv2
    float* h     = (float*)alloc((size_t)N * 256 * 4);
    float* out1  = (float*)alloc((size_t)N * 256 * 4);
    // h dead after conv1 aggregation -> reuse its region for h2/out2
    float* h2   = h;
    float* out2 = h + (size_t)N * 128;
    // out1 dead after h2 GEMM -> reuse its region for y1 [N,64]
    float* y1   = out1;

    int gN = (N + 255) / 256;
    int gE = (E + 255) / 256;
    int gW = (N + 3) / 4;  // wave-per-node kernels, 4 waves/block

    init_kernel<<<gN, 256, 0, stream>>>(deg1, deg2, counts, N);
    geo_dot<<<gN, 256, 0, stream>>>(coords, W_geom, geo_s, geo_d, N);
    dual_dot<512><<<gW, 256, 0, stream>>>(x, W_app, app_s, app_d, N);
    edge_phase1<<<gE, 256, 0, stream>>>(src1, dst1, app_s, app_d, geo_s, geo_d,
                                        b_app, b_geom, W_aff, b_aff, ew, deg1, counts, E);
    rsqrt_kernel<<<gN, 256, 0, stream>>>(deg1, dinv1, N);
    scan_kernel<<<1, 1024, 0, stream>>>(counts, offsets, cursor, N);
    scatter_kernel<<<gE, 256, 0, stream>>>(dst1, cursor, eid, E);
    build_csr1<<<gE, 256, 0, stream>>>(eid, src1, dinv1, ew, csr_src, csr_a, E);

    // h = x @ W_c1  [N,512]x[512,256]
    gemm64<<<dim3((N + 63) / 64, 256 / 64), 256, 0, stream>>>(x, W_c1, h, N, 256, 512);
    // out1 = relu(agg(h) + b_c1)
    conv_agg<256, true><<<gW, 256, 0, stream>>>(h, dinv1, csr_src, csr_a, offsets, b_c1, out1, N);

    // m_s/m_d from out1, edge_attr2, deg2
    dual_dot<256><<<gW, 256, 0, stream>>>(out1, W_m1, m_s, m_d, N);
    edge_phase2<<<gE, 256, 0, stream>>>(src1, dst1, m_s, m_d, b_m1, ew2, deg2, E);
    rsqrt_kernel<<<gN, 256, 0, stream>>>(deg2, dinv2, N);
    build_csr2<<<gE, 256, 0, stream>>>(eid, csr_src, dinv2, ew2, csr_a, E);

    // h2 = out1 @ W_c2  [N,256]x[256,128]
    gemm64<<<dim3((N + 63) / 64, 128 / 64), 256, 0, stream>>>(out1, W_c2, h2, N, 128, 256);
    // out2 = agg(h2) + b_c2 (no relu)
    conv_agg<128, false><<<gW, 256, 0, stream>>>(h2, dinv2, csr_src, csr_a, offsets, b_c2, out2, N);

    // y1 = out2 @ W_f1  [N,128]x[128,64]  (linear part distributes over the edge diff)
    gemm64<<<dim3((N + 63) / 64, 1), 256, 0, stream>>>(out2, W_f1, y1, N, 64, 128);

    // final pairwise classifier on edge_index2
    final_edge<<<E / 16, 256, 0, stream>>>(y1, e2a, e2b, b_f1, W_f2, b_f2, out, E);
}

// Round 3
// 484.950 us; speedup vs baseline: 2.1101x; 1.6201x over previous
//
#include <hip/hip_runtime.h>
#include <math.h>

#define NN 50000
#define NE 800000

typedef __attribute__((ext_vector_type(8))) short bf16x8;
typedef __attribute__((ext_vector_type(4))) float f32x4;

__device__ __forceinline__ float bf2f(ushort u) { return __uint_as_float(((unsigned)u) << 16); }
__device__ __forceinline__ ushort f2bf(float f) {
    unsigned b = __float_as_uint(f);
    return (ushort)((b + 0x7FFFu + ((b >> 16) & 1u)) >> 16);
}
__device__ __forceinline__ void load_lds16(const ushort* g, ushort* l) {
    __builtin_amdgcn_global_load_lds((const __attribute__((address_space(1))) unsigned int*)g,
                                     (__attribute__((address_space(3))) unsigned int*)l, 16, 0, 0);
}

// ---------------- init ----------------
__global__ void init_kernel(float* deg1, float* deg2, int* counts, int n) {
    int i = blockIdx.x * blockDim.x + threadIdx.x;
    if (i < n) { deg1[i] = 1.f; deg2[i] = 1.f; counts[i] = 0; }
}

// ---------------- conversions ----------------
__global__ void cvt_bf16_vec(const float* __restrict__ in, ushort* __restrict__ out, int n4) {
    int i = blockIdx.x * blockDim.x + threadIdx.x;
    if (i >= n4) return;
    float4 v = reinterpret_cast<const float4*>(in)[i];
    ushort4 o;
    o.x = f2bf(v.x); o.y = f2bf(v.y); o.z = f2bf(v.z); o.w = f2bf(v.w);
    reinterpret_cast<ushort4*>(out)[i] = o;
}

// WT[n*K+k] = bf16(W[k*N+n])
__global__ void cvt_wT(const float* __restrict__ W, ushort* __restrict__ WT, int K, int N) {
    int idx = blockIdx.x * blockDim.x + threadIdx.x;
    if (idx >= K * N) return;
    int k = idx / N, n = idx % N;
    WT[n * K + k] = f2bf(W[idx]);
}

// ---------------- geo dots ----------------
__global__ void geo_dot(const float* __restrict__ coords, const float* __restrict__ Wg,
                        float* __restrict__ geo_s, float* __restrict__ geo_d, int n) {
    int i = blockIdx.x * blockDim.x + threadIdx.x;
    if (i >= n) return;
    float4 c = *reinterpret_cast<const float4*>(coords + (size_t)i * 4);
    geo_s[i] = c.x * Wg[0] + c.y * Wg[1] + c.z * Wg[2] + c.w * Wg[3];
    geo_d[i] = c.x * Wg[4] + c.y * Wg[5] + c.z * Wg[6] + c.w * Wg[7];
}

// ---------------- dual dot on bf16 X: outs=X[n]·W[0:C], outd=X[n]·W[C:2C] ----------------
template <int C>
__global__ void dual_dot_bf(const ushort* __restrict__ X, const float* __restrict__ W,
                            float* __restrict__ outs, float* __restrict__ outd, int n) {
    constexpr int V = C / 64;  // 8 or 4
    int lane = threadIdx.x & 63, wid = threadIdx.x >> 6;
    int node = blockIdx.x * (blockDim.x >> 6) + wid;
    if (node >= n) return;
    const ushort* xr = X + (size_t)node * C + lane * V;
    const float* ws = W + lane * V;
    const float* wd = W + C + lane * V;
    float ss = 0.f, dd = 0.f;
#pragma unroll
    for (int v = 0; v < V; v += 4) {
        ushort4 xv = *reinterpret_cast<const ushort4*>(xr + v);
        float4 a = *reinterpret_cast<const float4*>(ws + v);
        float4 b = *reinterpret_cast<const float4*>(wd + v);
        float x0 = bf2f(xv.x), x1 = bf2f(xv.y), x2 = bf2f(xv.z), x3 = bf2f(xv.w);
        ss += x0 * a.x + x1 * a.y + x2 * a.z + x3 * a.w;
        dd += x0 * b.x + x1 * b.y + x2 * b.z + x3 * b.w;
    }
#pragma unroll
    for (int off = 32; off > 0; off >>= 1) {
        ss += __shfl_down(ss, off, 64);
        dd += __shfl_down(dd, off, 64);
    }
    if (lane == 0) { outs[node] = ss; outd[node] = dd; }
}

// ---------------- edge phase 1 ----------------
__global__ void edge_phase1(const int* __restrict__ src, const int* __restrict__ dst,
                            const float* __restrict__ app_s, const float* __restrict__ app_d,
                            const float* __restrict__ geo_s, const float* __restrict__ geo_d,
                            const float* __restrict__ b_app, const float* __restrict__ b_geom,
                            const float* __restrict__ W_aff, const float* __restrict__ b_aff,
                            float* __restrict__ ew, float* __restrict__ deg1,
                            int* __restrict__ counts, int E) {
    int e = blockIdx.x * blockDim.x + threadIdx.x;
    if (e >= E) return;
    int s = src[e], d = dst[e];
    float x1 = fmaxf(app_s[s] + app_d[d] + b_app[0], 0.f);
    float x2 = fmaxf(geo_s[s] + geo_d[d] + b_geom[0], 0.f);
    float w = fmaxf(x1 * W_aff[0] + x2 * W_aff[1] + b_aff[0], 0.f);
    ew[e] = w;
    atomicAdd(&deg1[d], w);
    atomicAdd(&counts[d], 1);
}

// ---------------- edge phase 2 in CSR-slot order ----------------
__global__ void phase2_slot(const int* __restrict__ eid, const int* __restrict__ csr_src,
                            const int* __restrict__ dst,
                            const float* __restrict__ m_s, const float* __restrict__ m_d,
                            const float* __restrict__ b_m1,
                            float* __restrict__ csr_a, float* __restrict__ deg2, int E) {
    int j = blockIdx.x * blockDim.x + threadIdx.x;
    if (j >= E) return;
    int e = eid[j];
    int s = csr_src[j];
    int d = dst[e];
    float w = fmaxf(m_s[s] + m_d[d] + b_m1[0], 0.f);
    csr_a[j] = w;
    atomicAdd(&deg2[d], w);
}

__global__ void scale_csr(const int* __restrict__ csr_src, const float* __restrict__ dinv,
                          float* __restrict__ csr_a, int E) {
    int j = blockIdx.x * blockDim.x + threadIdx.x;
    if (j >= E) return;
    csr_a[j] *= dinv[csr_src[j]];
}

// ---------------- dinv ----------------
__global__ void rsqrt_kernel(const float* __restrict__ deg, float* __restrict__ dinv, int n) {
    int i = blockIdx.x * blockDim.x + threadIdx.x;
    if (i >= n) return;
    float dg = deg[i];
    dinv[i] = dg > 0.f ? rsqrtf(fmaxf(dg, 1e-12f)) : 0.f;
}

// ---------------- single-block exclusive scan ----------------
__global__ __launch_bounds__(1024) void scan_kernel(const int* __restrict__ counts,
                                                    int* __restrict__ offsets,
                                                    int* __restrict__ cursor, int n) {
    __shared__ int wsum[16];
    __shared__ int carry_sh;
    int tid = threadIdx.x, lane = tid & 63, wid = tid >> 6;
    int running = 0;
    for (int base = 0; base < n; base += 4096) {
        int i0 = base + tid * 4;
        int4 v;
        if (i0 + 3 < n) v = *reinterpret_cast<const int4*>(counts + i0);
        else {
            v.x = (i0 + 0 < n) ? counts[i0 + 0] : 0;
            v.y = (i0 + 1 < n) ? counts[i0 + 1] : 0;
            v.z = (i0 + 2 < n) ? counts[i0 + 2] : 0;
            v.w = (i0 + 3 < n) ? counts[i0 + 3] : 0;
        }
        int tot = v.x + v.y + v.z + v.w;
        int inc = tot;
#pragma unroll
        for (int off = 1; off < 64; off <<= 1) {
            int t = __shfl_up(inc, off, 64);
            if (lane >= off) inc += t;
        }
        if (lane == 63) wsum[wid] = inc;
        __syncthreads();
        if (tid == 0) {
            int s = 0;
#pragma unroll
            for (int w = 0; w < 16; ++w) { int t = wsum[w]; wsum[w] = s; s += t; }
            carry_sh = s;
        }
        __syncthreads();
        int ex = running + wsum[wid] + (inc - tot);
        int4 o;
        o.x = ex; o.y = ex + v.x; o.z = ex + v.x + v.y; o.w = ex + v.x + v.y + v.z;
        if (i0 + 3 < n) {
            *reinterpret_cast<int4*>(offsets + i0) = o;
            *reinterpret_cast<int4*>(cursor + i0) = o;
        } else {
            if (i0 + 0 < n) { offsets[i0 + 0] = o.x; cursor[i0 + 0] = o.x; }
            if (i0 + 1 < n) { offsets[i0 + 1] = o.y; cursor[i0 + 1] = o.y; }
            if (i0 + 2 < n) { offsets[i0 + 2] = o.z; cursor[i0 + 2] = o.z; }
            if (i0 + 3 < n) { offsets[i0 + 3] = o.w; cursor[i0 + 3] = o.w; }
        }
        running += carry_sh;
        __syncthreads();
    }
    if (tid == 0) offsets[n] = running;
}

// ---------------- CSR scatter ----------------
__global__ void scatter_kernel(const int* __restrict__ dst, int* __restrict__ cursor,
                               int* __restrict__ eid, int E) {
    int e = blockIdx.x * blockDim.x + threadIdx.x;
    if (e >= E) return;
    int pos = atomicAdd(&cursor[dst[e]], 1);
    eid[pos] = e;
}

__global__ void build_csr1(const int* __restrict__ eid, const int* __restrict__ src,
                           const float* __restrict__ dinv, const float* __restrict__ ew,
                           int* __restrict__ csr_src, float* __restrict__ csr_a, int E) {
    int j = blockIdx.x * blockDim.x + threadIdx.x;
    if (j >= E) return;
    int e = eid[j];
    int s = src[e];
    csr_src[j] = s;
    csr_a[j] = dinv[s] * ew[e];
}

// ---------------- MFMA bf16 GEMM: C[M,N] = A[M,K] * BT[N,K]^T ----------------
// A row-major bf16 (M padded to >= gridDim.x*128 rows allocated), BT row-major bf16 [N][K].
// LDS XOR-swizzle: 16B slot s of row r holds global slot s^(r&7) (pre-swizzled global src).
template <int WAVES_N, int MF, int NF, bool OUT_BF>
__global__ __launch_bounds__(256) void mfma_gemm(const ushort* __restrict__ A,
                                                 const ushort* __restrict__ BT,
                                                 void* __restrict__ Cout,
                                                 int M, int N, int K) {
    constexpr int WAVES_M = 4 / WAVES_N;
    constexpr int BM = WAVES_M * MF * 16;
    constexpr int BN = WAVES_N * NF * 16;
    constexpr int BK = 64;
    static_assert(BM == 128, "BM must be 128");
    __shared__ __align__(16) ushort As[BM * BK];
    __shared__ __align__(16) ushort Bs[BN * BK];
    const int tid = threadIdx.x;
    const int lane = tid & 63, wid = tid >> 6;
    const int wr = wid / WAVES_N, wc = wid % WAVES_N;
    const int m_blk = blockIdx.x * BM;
    const int n_blk = blockIdx.y * BN;

    // staging constants: thread covers 16B slot (tid&7) of rows (i*32 + tid>>3)
    const int slot = tid & 7;
    const int brow = tid >> 3;
    const int xslot = slot ^ (brow & 7);  // (i*32) & 7 == 0 so row&7 == brow&7
    constexpr int ISS_A = BM / 32;
    constexpr int ISS_B = BN / 32;

    f32x4 acc[MF][NF];
#pragma unroll
    for (int i = 0; i < MF; ++i)
#pragma unroll
        for (int j = 0; j < NF; ++j) acc[i][j] = (f32x4){0.f, 0.f, 0.f, 0.f};

    const int frag_r_a = wr * (MF * 16) + (lane & 15);
    const int frag_r_b = wc * (NF * 16) + (lane & 15);
    const int frag_s = lane >> 4;  // 0..3

    const int nkt = K >> 6;
    for (int kt = 0; kt < nkt; ++kt) {
        const long kbase = (long)kt * 64;
#pragma unroll
        for (int i = 0; i < ISS_A; ++i) {
            int row = i * 32 + brow;
            const ushort* g = A + (long)(m_blk + row) * K + kbase + xslot * 8;
            load_lds16(g, As + i * 2048 + wid * 512);
        }
#pragma unroll
        for (int i = 0; i < ISS_B; ++i) {
            int row = i * 32 + brow;
            const ushort* g = BT + (long)(n_blk + row) * K + kbase + xslot * 8;
            load_lds16(g, Bs + i * 2048 + wid * 512);
        }
        asm volatile("s_waitcnt vmcnt(0)" ::: "memory");
        __syncthreads();
#pragma unroll
        for (int ks = 0; ks < 2; ++ks) {
            bf16x8 av[MF], bv[NF];
#pragma unroll
            for (int mf = 0; mf < MF; ++mf) {
                int r = frag_r_a + mf * 16;
                int s = ks * 4 + frag_s;
                av[mf] = *reinterpret_cast<const bf16x8*>(As + r * BK + ((s ^ (r & 7)) << 3));
            }
#pragma unroll
            for (int nf = 0; nf < NF; ++nf) {
                int r = frag_r_b + nf * 16;
                int s = ks * 4 + frag_s;
                bv[nf] = *reinterpret_cast<const bf16x8*>(Bs + r * BK + ((s ^ (r & 7)) << 3));
            }
#pragma unroll
            for (int mf = 0; mf < MF; ++mf)
#pragma unroll
                for (int nf = 0; nf < NF; ++nf)
                    acc[mf][nf] = __builtin_amdgcn_mfma_f32_16x16x32_bf16(av[mf], bv[nf], acc[mf][nf], 0, 0, 0);
        }
        __syncthreads();
    }
    // epilogue: D col = lane&15, row = (lane>>4)*4 + reg
    const int col0 = n_blk + wc * NF * 16 + (lane & 15);
    const int row0 = m_blk + wr * MF * 16 + ((lane >> 4) << 2);
#pragma unroll
    for (int mf = 0; mf < MF; ++mf) {
#pragma unroll
        for (int r = 0; r < 4; ++r) {
            int row = row0 + mf * 16 + r;
            if (row < M) {
#pragma unroll
                for (int nf = 0; nf < NF; ++nf) {
                    if (OUT_BF)
                        ((ushort*)Cout)[(long)row * N + col0 + nf * 16] = f2bf(acc[mf][nf][r]);
                    else
                        ((float*)Cout)[(long)row * N + col0 + nf * 16] = acc[mf][nf][r];
                }
            }
        }
    }
}

// ---------------- GCN aggregation over bf16 features ----------------
// out[node] = bf16( dinv[n]*(dinv[n]*h[n] + sum_j csr_a[j]*h[csr_src[j]]) + bias )
template <int C, bool RELU>
__global__ void conv_agg_bf(const ushort* __restrict__ h, const float* __restrict__ dinv,
                            const int* __restrict__ csr_src, const float* __restrict__ csr_a,
                            const int* __restrict__ offsets, const float* __restrict__ bias,
                            ushort* __restrict__ out, int n) {
    constexpr int V = C / 64;  // 4 or 2
    int lane = threadIdx.x & 63, wid = threadIdx.x >> 6;
    int node = blockIdx.x * (blockDim.x >> 6) + wid;
    if (node >= n) return;
    float dn = dinv[node];
    float acc[V];
    {
        const ushort* hn = h + (size_t)node * C + lane * V;
        if constexpr (V == 4) {
            ushort4 v = *reinterpret_cast<const ushort4*>(hn);
            acc[0] = dn * bf2f(v.x); acc[1] = dn * bf2f(v.y);
            acc[2] = dn * bf2f(v.z); acc[3] = dn * bf2f(v.w);
        } else {
            ushort2 v = *reinterpret_cast<const ushort2*>(hn);
            acc[0] = dn * bf2f(v.x); acc[1] = dn * bf2f(v.y);
        }
    }
    int j0 = offsets[node], j1 = offsets[node + 1];
    int j = j0;
    for (; j + 4 <= j1; j += 4) {
        int s0 = csr_src[j], s1 = csr_src[j + 1], s2 = csr_src[j + 2], s3 = csr_src[j + 3];
        float a0 = csr_a[j], a1 = csr_a[j + 1], a2 = csr_a[j + 2], a3 = csr_a[j + 3];
        if constexpr (V == 4) {
            ushort4 v0 = *reinterpret_cast<const ushort4*>(h + (size_t)s0 * C + lane * 4);
            ushort4 v1 = *reinterpret_cast<const ushort4*>(h + (size_t)s1 * C + lane * 4);
            ushort4 v2 = *reinterpret_cast<const ushort4*>(h + (size_t)s2 * C + lane * 4);
            ushort4 v3 = *reinterpret_cast<const ushort4*>(h + (size_t)s3 * C + lane * 4);
            acc[0] += a0 * bf2f(v0.x) + a1 * bf2f(v1.x) + a2 * bf2f(v2.x) + a3 * bf2f(v3.x);
            acc[1] += a0 * bf2f(v0.y) + a1 * bf2f(v1.y) + a2 * bf2f(v2.y) + a3 * bf2f(v3.y);
            acc[2] += a0 * bf2f(v0.z) + a1 * bf2f(v1.z) + a2 * bf2f(v2.z) + a3 * bf2f(v3.z);
            acc[3] += a0 * bf2f(v0.w) + a1 * bf2f(v1.w) + a2 * bf2f(v2.w) + a3 * bf2f(v3.w);
        } else {
            ushort2 v0 = *reinterpret_cast<const ushort2*>(h + (size_t)s0 * C + lane * 2);
            ushort2 v1 = *reinterpret_cast<const ushort2*>(h + (size_t)s1 * C + lane * 2);
            ushort2 v2 = *reinterpret_cast<const ushort2*>(h + (size_t)s2 * C + lane * 2);
            ushort2 v3 = *reinterpret_cast<const ushort2*>(h + (size_t)s3 * C + lane * 2);
            acc[0] += a0 * bf2f(v0.x) + a1 * bf2f(v1.x) + a2 * bf2f(v2.x) + a3 * bf2f(v3.x);
            acc[1] += a0 * bf2f(v0.y) + a1 * bf2f(v1.y) + a2 * bf2f(v2.y) + a3 * bf2f(v3.y);
        }
    }
    for (; j < j1; ++j) {
        int s = csr_src[j];
        float a = csr_a[j];
        const ushort* hs = h + (size_t)s * C + lane * V;
        if constexpr (V == 4) {
            ushort4 v = *reinterpret_cast<const ushort4*>(hs);
            acc[0] += a * bf2f(v.x); acc[1] += a * bf2f(v.y);
            acc[2] += a * bf2f(v.z); acc[3] += a * bf2f(v.w);
        } else {
            ushort2 v = *reinterpret_cast<const ushort2*>(hs);
            acc[0] += a * bf2f(v.x); acc[1] += a * bf2f(v.y);
        }
    }
    const float* bp = bias + lane * V;
    ushort* op = out + (size_t)node * C + lane * V;
    if constexpr (V == 4) {
        ushort4 o;
        float o0 = acc[0] * dn + bp[0], o1 = acc[1] * dn + bp[1];
        float o2 = acc[2] * dn + bp[2], o3 = acc[3] * dn + bp[3];
        if (RELU) { o0 = fmaxf(o0, 0.f); o1 = fmaxf(o1, 0.f); o2 = fmaxf(o2, 0.f); o3 = fmaxf(o3, 0.f); }
        o.x = f2bf(o0); o.y = f2bf(o1); o.z = f2bf(o2); o.w = f2bf(o3);
        *reinterpret_cast<ushort4*>(op) = o;
    } else {
        ushort2 o;
        float o0 = acc[0] * dn + bp[0], o1 = acc[1] * dn + bp[1];
        if (RELU) { o0 = fmaxf(o0, 0.f); o1 = fmaxf(o1, 0.f); }
        o.x = f2bf(o0); o.y = f2bf(o1);
        *reinterpret_cast<ushort2*>(op) = o;
    }
}

// ---------------- final pairwise classifier on y1 = out2 @ W_f1 ----------------
__global__ __launch_bounds__(256) void final_edge(const float* __restrict__ y1,
                                                  const int* __restrict__ ea,
                                                  const int* __restrict__ eb,
                                                  const float* __restrict__ b_f1,
                                                  const float* __restrict__ W_f2,
                                                  const float* __restrict__ b_f2,
                                                  float* __restrict__ out, int E) {
    int lane = threadIdx.x & 63, wid = threadIdx.x >> 6;
    int sub = lane >> 4, k4 = lane & 15;
    int wave = blockIdx.x * 4 + wid;
    int e = wave * 4 + sub;
    if (e >= E) return;
    float4 bf1 = *reinterpret_cast<const float4*>(b_f1 + k4 * 4);
    float4 wf2 = *reinterpret_cast<const float4*>(W_f2 + k4 * 4);
    int a = ea[e], b = eb[e];
    float4 va = *reinterpret_cast<const float4*>(y1 + (size_t)a * 64 + k4 * 4);
    float4 vb = *reinterpret_cast<const float4*>(y1 + (size_t)b * 64 + k4 * 4);
    float p = fmaxf(va.x - vb.x + bf1.x, 0.f) * wf2.x
            + fmaxf(va.y - vb.y + bf1.y, 0.f) * wf2.y
            + fmaxf(va.z - vb.z + bf1.z, 0.f) * wf2.z
            + fmaxf(va.w - vb.w + bf1.w, 0.f) * wf2.w;
    p += __shfl_xor(p, 1, 64);
    p += __shfl_xor(p, 2, 64);
    p += __shfl_xor(p, 4, 64);
    p += __shfl_xor(p, 8, 64);
    if (k4 == 0) out[e] = 1.f / (1.f + expf(-(p + b_f2[0])));
}

extern "C" void kernel_launch(void* const* d_in, const int* in_sizes, int n_in,
                              void* d_out, int out_size, void* d_ws, size_t ws_size,
                              hipStream_t stream) {
    const float* x      = (const float*)d_in[0];
    const float* coords = (const float*)d_in[1];
    const float* W_app  = (const float*)d_in[2];
    const float* b_app  = (const float*)d_in[3];
    const float* W_geom = (const float*)d_in[4];
    const float* b_geom = (const float*)d_in[5];
    const float* W_aff  = (const float*)d_in[6];
    const float* b_aff  = (const float*)d_in[7];
    const float* W_c1   = (const float*)d_in[8];
    const float* b_c1   = (const float*)d_in[9];
    const float* W_m1   = (const float*)d_in[10];
    const float* b_m1   = (const float*)d_in[11];
    const float* W_c2   = (const float*)d_in[12];
    const float* b_c2   = (const float*)d_in[13];
    const float* W_f1   = (const float*)d_in[14];
    const float* b_f1   = (const float*)d_in[15];
    const float* W_f2   = (const float*)d_in[16];
    const float* b_f2   = (const float*)d_in[17];
    const int*   e1     = (const int*)d_in[18];
    const int*   e2     = (const int*)d_in[19];
    float* out = (float*)d_out;

    const int N = NN;
    const int E = NE;
    const int MP = 50048;  // M padded to 391*128
    const int* src1 = e1;
    const int* dst1 = e1 + E;
    const int* e2a = e2;
    const int* e2b = e2 + E;

    char* ws = (char*)d_ws;
    size_t off = 0;
    auto alloc = [&](size_t bytes) -> void* {
        void* p = ws + off;
        off += (bytes + 255) & ~(size_t)255;
        return p;
    };
    float* app_s = (float*)alloc((size_t)N * 4);
    float* app_d = (float*)alloc((size_t)N * 4);
    float* geo_s = (float*)alloc((size_t)N * 4);
    float* geo_d = (float*)alloc((size_t)N * 4);
    float* m_s   = (float*)alloc((size_t)N * 4);
    float* m_d   = (float*)alloc((size_t)N * 4);
    float* deg1  = (float*)alloc((size_t)N * 4);
    float* dinv1 = (float*)alloc((size_t)N * 4);
    float* deg2  = (float*)alloc((size_t)N * 4);
    float* dinv2 = (float*)alloc((size_t)N * 4);
    int* counts  = (int*)alloc((size_t)N * 4);
    int* offsets = (int*)alloc((size_t)(N + 1) * 4);
    int* cursor  = (int*)alloc((size_t)N * 4);
    int* eid     = (int*)alloc((size_t)E * 4);
    float* ew    = (float*)alloc((size_t)E * 4);
    int* csr_src = (int*)alloc((size_t)E * 4);
    float* csr_a = (float*)alloc((size_t)E * 4);
    ushort* wc1T = (ushort*)alloc((size_t)256 * 512 * 2);
    ushort* wc2T = (ushort*)alloc((size_t)128 * 256 * 2);
    ushort* wf1T = (ushort*)alloc((size_t)64 * 128 * 2);
    ushort* x_bf = (ushort*)alloc((size_t)MP * 512 * 2);   // 51.25 MB
    ushort* h_bf = (ushort*)alloc((size_t)MP * 256 * 2);   // 25.62 MB, reused later
    ushort* out1b = (ushort*)alloc((size_t)MP * 256 * 2);  // 25.62 MB, reused later
    // overlays (regions dead by the time these are written):
    ushort* h2b   = h_bf;                                  // [N,128] bf16 (h_bf dead after conv1)
    ushort* out2b = h_bf + (size_t)N * 128;                // [MP,128] bf16
    float*  y1    = (float*)out1b;                         // [N,64] f32 (out1b dead after gemm2)

    int gN = (N + 255) / 256;
    int gE = (E + 255) / 256;
    int gW = (N + 3) / 4;

    init_kernel<<<gN, 256, 0, stream>>>(deg1, deg2, counts, N);
    cvt_bf16_vec<<<(N * 512 / 4 + 255) / 256, 256, 0, stream>>>(x, x_bf, N * 512 / 4);
    cvt_wT<<<(512 * 256 + 255) / 256, 256, 0, stream>>>(W_c1, wc1T, 512, 256);
    cvt_wT<<<(256 * 128 + 255) / 256, 256, 0, stream>>>(W_c2, wc2T, 256, 128);
    cvt_wT<<<(128 * 64 + 255) / 256, 256, 0, stream>>>(W_f1, wf1T, 128, 64);
    geo_dot<<<gN, 256, 0, stream>>>(coords, W_geom, geo_s, geo_d, N);
    dual_dot_bf<512><<<gW, 256, 0, stream>>>(x_bf, W_app, app_s, app_d, N);
    edge_phase1<<<gE, 256, 0, stream>>>(src1, dst1, app_s, app_d, geo_s, geo_d,
                                        b_app, b_geom, W_aff, b_aff, ew, deg1, counts, E);
    rsqrt_kernel<<<gN, 256, 0, stream>>>(deg1, dinv1, N);
    scan_kernel<<<1, 1024, 0, stream>>>(counts, offsets, cursor, N);
    scatter_kernel<<<gE, 256, 0, stream>>>(dst1, cursor, eid, E);
    build_csr1<<<gE, 256, 0, stream>>>(eid, src1, dinv1, ew, csr_src, csr_a, E);

    // h_bf = bf16(x @ W_c1)  [50000,512]x[512,256]
    mfma_gemm<2, 4, 4, true><<<dim3(MP / 128, 2), 256, 0, stream>>>(x_bf, wc1T, h_bf, N, 256, 512);
    // out1b = bf16(relu(agg(h_bf) + b_c1))
    conv_agg_bf<256, true><<<gW, 256, 0, stream>>>(h_bf, dinv1, csr_src, csr_a, offsets, b_c1, out1b, N);

    // m_s/m_d from out1b; edge weights 2 (slot-ordered), deg2, scale
    dual_dot_bf<256><<<gW, 256, 0, stream>>>(out1b, W_m1, m_s, m_d, N);
    phase2_slot<<<gE, 256, 0, stream>>>(eid, csr_src, dst1, m_s, m_d, b_m1, csr_a, deg2, E);
    rsqrt_kernel<<<gN, 256, 0, stream>>>(deg2, dinv2, N);
    scale_csr<<<gE, 256, 0, stream>>>(csr_src, dinv2, csr_a, E);

    // h2b = bf16(out1b @ W_c2)  [50000,256]x[256,128]   (into dead h_bf region)
    mfma_gemm<2, 4, 4, true><<<dim3(MP / 128, 1), 256, 0, stream>>>(out1b, wc2T, h2b, N, 128, 256);
    // out2b = bf16(agg(h2b) + b_c2)
    conv_agg_bf<128, false><<<gW, 256, 0, stream>>>(h2b, dinv2, csr_src, csr_a, offsets, b_c2, out2b, N);

    // y1 = out2b @ W_f1  [50000,128]x[128,64] -> f32   (into dead out1b region)
    mfma_gemm<1, 2, 4, false><<<dim3(MP / 128, 1), 256, 0, stream>>>(out2b, wf1T, y1, N, 64, 128);

    // final pairwise classifier
    final_edge<<<E / 16, 256, 0, stream>>>(y1, e2a, e2b, b_f1, W_f2, b_f2, out, E);
}

// Round 4
// 349.637 us; speedup vs baseline: 2.9268x; 1.3870x over previous
//
#include <hip/hip_runtime.h>
#include <math.h>

#define NN 50000
#define NE 800000

typedef __attribute__((ext_vector_type(8))) short bf16x8;
typedef __attribute__((ext_vector_type(8))) unsigned short ushortx8;
typedef __attribute__((ext_vector_type(4))) float f32x4;

__device__ __forceinline__ float bf2f(ushort u) { return __uint_as_float(((unsigned)u) << 16); }
__device__ __forceinline__ ushort f2bf(float f) {
    unsigned b = __float_as_uint(f);
    return (ushort)((b + 0x7FFFu + ((b >> 16) & 1u)) >> 16);
}
__device__ __forceinline__ void load_lds16(const ushort* g, ushort* l) {
    __builtin_amdgcn_global_load_lds((const __attribute__((address_space(1))) unsigned int*)g,
                                     (__attribute__((address_space(3))) unsigned int*)l, 16, 0, 0);
}

// ---------------- fused x prep: x -> bf16, app_s/app_d dots ----------------
__global__ void prep_x(const float* __restrict__ x, const float* __restrict__ W_app,
                       ushort* __restrict__ x_bf, float* __restrict__ app_s,
                       float* __restrict__ app_d, int n) {
    int lane = threadIdx.x & 63, wid = threadIdx.x >> 6;
    int node = blockIdx.x * 4 + wid;
    if (node >= n) return;
    const float* xr = x + (size_t)node * 512 + lane * 8;
    float4 a = *reinterpret_cast<const float4*>(xr);
    float4 b = *reinterpret_cast<const float4*>(xr + 4);
    float4 ws0 = *reinterpret_cast<const float4*>(W_app + lane * 8);
    float4 ws1 = *reinterpret_cast<const float4*>(W_app + lane * 8 + 4);
    float4 wd0 = *reinterpret_cast<const float4*>(W_app + 512 + lane * 8);
    float4 wd1 = *reinterpret_cast<const float4*>(W_app + 512 + lane * 8 + 4);
    float ss = a.x * ws0.x + a.y * ws0.y + a.z * ws0.z + a.w * ws0.w
             + b.x * ws1.x + b.y * ws1.y + b.z * ws1.z + b.w * ws1.w;
    float dd = a.x * wd0.x + a.y * wd0.y + a.z * wd0.z + a.w * wd0.w
             + b.x * wd1.x + b.y * wd1.y + b.z * wd1.z + b.w * wd1.w;
    ushortx8 o;
    o.s0 = f2bf(a.x); o.s1 = f2bf(a.y); o.s2 = f2bf(a.z); o.s3 = f2bf(a.w);
    o.s4 = f2bf(b.x); o.s5 = f2bf(b.y); o.s6 = f2bf(b.z); o.s7 = f2bf(b.w);
    *reinterpret_cast<ushortx8*>(x_bf + (size_t)node * 512 + lane * 8) = o;
#pragma unroll
    for (int off = 32; off > 0; off >>= 1) {
        ss += __shfl_down(ss, off, 64);
        dd += __shfl_down(dd, off, 64);
    }
    if (lane == 0) { app_s[node] = ss; app_d[node] = dd; }
}

// WT[n*K+k] = bf16(W[k*N+n])
__global__ void cvt_wT(const float* __restrict__ W, ushort* __restrict__ WT, int K, int N) {
    int idx = blockIdx.x * blockDim.x + threadIdx.x;
    if (idx >= K * N) return;
    int k = idx / N, n = idx % N;
    WT[n * K + k] = f2bf(W[idx]);
}

// ---------------- geo dots ----------------
__global__ void geo_dot(const float* __restrict__ coords, const float* __restrict__ Wg,
                        float* __restrict__ geo_s, float* __restrict__ geo_d, int n) {
    int i = blockIdx.x * blockDim.x + threadIdx.x;
    if (i >= n) return;
    float4 c = *reinterpret_cast<const float4*>(coords + (size_t)i * 4);
    geo_s[i] = c.x * Wg[0] + c.y * Wg[1] + c.z * Wg[2] + c.w * Wg[3];
    geo_d[i] = c.x * Wg[4] + c.y * Wg[5] + c.z * Wg[6] + c.w * Wg[7];
}

// ---------------- CSR rank (the ONLY far-atomic pass: 800k) ----------------
__global__ void scatter_rank(const int* __restrict__ dst, int* __restrict__ cursor,
                             int* __restrict__ rank, int E) {
    int e = blockIdx.x * blockDim.x + threadIdx.x;
    if (e >= E) return;
    rank[e] = atomicAdd(&cursor[dst[e]], 1);
}

// ---------------- single-block exclusive scan: counts -> offsets ----------------
__global__ __launch_bounds__(1024) void scan_kernel(const int* __restrict__ counts,
                                                    int* __restrict__ offsets, int n) {
    __shared__ int wsum[16];
    __shared__ int carry_sh;
    int tid = threadIdx.x, lane = tid & 63, wid = tid >> 6;
    int running = 0;
    for (int base = 0; base < n; base += 4096) {
        int i0 = base + tid * 4;
        int4 v;
        if (i0 + 3 < n) v = *reinterpret_cast<const int4*>(counts + i0);
        else {
            v.x = (i0 + 0 < n) ? counts[i0 + 0] : 0;
            v.y = (i0 + 1 < n) ? counts[i0 + 1] : 0;
            v.z = (i0 + 2 < n) ? counts[i0 + 2] : 0;
            v.w = (i0 + 3 < n) ? counts[i0 + 3] : 0;
        }
        int tot = v.x + v.y + v.z + v.w;
        int inc = tot;
#pragma unroll
        for (int off = 1; off < 64; off <<= 1) {
            int t = __shfl_up(inc, off, 64);
            if (lane >= off) inc += t;
        }
        if (lane == 63) wsum[wid] = inc;
        __syncthreads();
        if (tid == 0) {
            int s = 0;
#pragma unroll
            for (int w = 0; w < 16; ++w) { int t = wsum[w]; wsum[w] = s; s += t; }
            carry_sh = s;
        }
        __syncthreads();
        int ex = running + wsum[wid] + (inc - tot);
        int4 o;
        o.x = ex; o.y = ex + v.x; o.z = ex + v.x + v.y; o.w = ex + v.x + v.y + v.z;
        if (i0 + 3 < n) *reinterpret_cast<int4*>(offsets + i0) = o;
        else {
            if (i0 + 0 < n) offsets[i0 + 0] = o.x;
            if (i0 + 1 < n) offsets[i0 + 1] = o.y;
            if (i0 + 2 < n) offsets[i0 + 2] = o.z;
            if (i0 + 3 < n) offsets[i0 + 3] = o.w;
        }
        running += carry_sh;
        __syncthreads();
    }
    if (tid == 0) offsets[n] = running;
}

// ---------------- place: edge weight inline, no atomics ----------------
__global__ void place_fused(const int* __restrict__ src, const int* __restrict__ dst,
                            const int* __restrict__ rank, const int* __restrict__ offsets,
                            const float* __restrict__ app_s, const float* __restrict__ app_d,
                            const float* __restrict__ geo_s, const float* __restrict__ geo_d,
                            const float* __restrict__ b_app, const float* __restrict__ b_geom,
                            const float* __restrict__ W_aff, const float* __restrict__ b_aff,
                            int* __restrict__ csr_src, float* __restrict__ csr_ew, int E) {
    int e = blockIdx.x * blockDim.x + threadIdx.x;
    if (e >= E) return;
    int s = src[e], d = dst[e];
    float x1 = fmaxf(app_s[s] + app_d[d] + b_app[0], 0.f);
    float x2 = fmaxf(geo_s[s] + geo_d[d] + b_geom[0], 0.f);
    float w = fmaxf(x1 * W_aff[0] + x2 * W_aff[1] + b_aff[0], 0.f);
    int pos = offsets[d] + rank[e];
    csr_src[pos] = s;
    csr_ew[pos] = w;
}

// ---------------- deg/dinv from row sums (no atomics) ----------------
__global__ void deg_dinv(const float* __restrict__ w, const int* __restrict__ offsets,
                         float* __restrict__ dinv, int n) {
    int i = blockIdx.x * blockDim.x + threadIdx.x;
    if (i >= n) return;
    int j0 = offsets[i], j1 = offsets[i + 1];
    float s = 1.f;  // self-loop weight
    for (int j = j0; j < j1; ++j) s += w[j];
    dinv[i] = rsqrtf(s);
}

__global__ void scale_csr(const int* __restrict__ csr_src, const float* __restrict__ dinv,
                          const float* __restrict__ w, float* __restrict__ csr_a, int E) {
    int j = blockIdx.x * blockDim.x + threadIdx.x;
    if (j >= E) return;
    csr_a[j] = dinv[csr_src[j]] * w[j];
}

// ---------------- phase 2: edge weights + deg2 per row (no atomics) ----------------
// w2[j] = relu(m_s[csr_src[j]] + m_d[node] + b_m1); dinv2[node]=rsqrt(1+sum w2)
__global__ void phase2_rows(const int* __restrict__ csr_src, const int* __restrict__ offsets,
                            const float* __restrict__ m_s, const float* __restrict__ m_d,
                            const float* __restrict__ b_m1,
                            float* __restrict__ w2, float* __restrict__ dinv2, int n) {
    int i = blockIdx.x * blockDim.x + threadIdx.x;
    if (i >= n) return;
    float md = m_d[i] + b_m1[0];
    int j0 = offsets[i], j1 = offsets[i + 1];
    float s = 1.f;
    for (int j = j0; j < j1; ++j) {
        float w = fmaxf(m_s[csr_src[j]] + md, 0.f);
        w2[j] = w;
        s += w;
    }
    dinv2[i] = rsqrtf(s);
}

// ---------------- MFMA bf16 GEMM: C[M,N] = A[M,K] * BT[N,K]^T ----------------
template <int WAVES_N, int MF, int NF, bool OUT_BF>
__global__ __launch_bounds__(256) void mfma_gemm(const ushort* __restrict__ A,
                                                 const ushort* __restrict__ BT,
                                                 void* __restrict__ Cout,
                                                 int M, int N, int K) {
    constexpr int WAVES_M = 4 / WAVES_N;
    constexpr int BM = WAVES_M * MF * 16;
    constexpr int BN = WAVES_N * NF * 16;
    constexpr int BK = 64;
    static_assert(BM == 128, "BM must be 128");
    __shared__ __align__(16) ushort As[BM * BK];
    __shared__ __align__(16) ushort Bs[BN * BK];
    const int tid = threadIdx.x;
    const int lane = tid & 63, wid = tid >> 6;
    const int wr = wid / WAVES_N, wc = wid % WAVES_N;
    const int m_blk = blockIdx.x * BM;
    const int n_blk = blockIdx.y * BN;

    const int slot = tid & 7;
    const int brow = tid >> 3;
    const int xslot = slot ^ (brow & 7);
    constexpr int ISS_A = BM / 32;
    constexpr int ISS_B = BN / 32;

    f32x4 acc[MF][NF];
#pragma unroll
    for (int i = 0; i < MF; ++i)
#pragma unroll
        for (int j = 0; j < NF; ++j) acc[i][j] = (f32x4){0.f, 0.f, 0.f, 0.f};

    const int frag_r_a = wr * (MF * 16) + (lane & 15);
    const int frag_r_b = wc * (NF * 16) + (lane & 15);
    const int frag_s = lane >> 4;

    const int nkt = K >> 6;
    for (int kt = 0; kt < nkt; ++kt) {
        const long kbase = (long)kt * 64;
#pragma unroll
        for (int i = 0; i < ISS_A; ++i) {
            int row = i * 32 + brow;
            const ushort* g = A + (long)(m_blk + row) * K + kbase + xslot * 8;
            load_lds16(g, As + i * 2048 + wid * 512);
        }
#pragma unroll
        for (int i = 0; i < ISS_B; ++i) {
            int row = i * 32 + brow;
            const ushort* g = BT + (long)(n_blk + row) * K + kbase + xslot * 8;
            load_lds16(g, Bs + i * 2048 + wid * 512);
        }
        asm volatile("s_waitcnt vmcnt(0)" ::: "memory");
        __syncthreads();
#pragma unroll
        for (int ks = 0; ks < 2; ++ks) {
            bf16x8 av[MF], bv[NF];
#pragma unroll
            for (int mf = 0; mf < MF; ++mf) {
                int r = frag_r_a + mf * 16;
                int s = ks * 4 + frag_s;
                av[mf] = *reinterpret_cast<const bf16x8*>(As + r * BK + ((s ^ (r & 7)) << 3));
            }
#pragma unroll
            for (int nf = 0; nf < NF; ++nf) {
                int r = frag_r_b + nf * 16;
                int s = ks * 4 + frag_s;
                bv[nf] = *reinterpret_cast<const bf16x8*>(Bs + r * BK + ((s ^ (r & 7)) << 3));
            }
#pragma unroll
            for (int mf = 0; mf < MF; ++mf)
#pragma unroll
                for (int nf = 0; nf < NF; ++nf)
                    acc[mf][nf] = __builtin_amdgcn_mfma_f32_16x16x32_bf16(av[mf], bv[nf], acc[mf][nf], 0, 0, 0);
        }
        __syncthreads();
    }
    const int col0 = n_blk + wc * NF * 16 + (lane & 15);
    const int row0 = m_blk + wr * MF * 16 + ((lane >> 4) << 2);
#pragma unroll
    for (int mf = 0; mf < MF; ++mf) {
#pragma unroll
        for (int r = 0; r < 4; ++r) {
            int row = row0 + mf * 16 + r;
            if (row < M) {
#pragma unroll
                for (int nf = 0; nf < NF; ++nf) {
                    if (OUT_BF)
                        ((ushort*)Cout)[(long)row * N + col0 + nf * 16] = f2bf(acc[mf][nf][r]);
                    else
                        ((float*)Cout)[(long)row * N + col0 + nf * 16] = acc[mf][nf][r];
                }
            }
        }
    }
}

// ---------------- GCN aggregation over bf16 features ----------------
// out[node] = bf16( dinv[n]*(dinv[n]*h[n] + sum_j csr_a[j]*h[csr_src[j]]) + bias )
// FUSE: also emit m_s/m_d = out_row . W_m1 halves.
template <int C, bool RELU, bool FUSE>
__global__ void conv_agg_bf(const ushort* __restrict__ h, const float* __restrict__ dinv,
                            const int* __restrict__ csr_src, const float* __restrict__ csr_a,
                            const int* __restrict__ offsets, const float* __restrict__ bias,
                            ushort* __restrict__ out,
                            const float* __restrict__ W_m1, float* __restrict__ m_s,
                            float* __restrict__ m_d, int n) {
    constexpr int V = C / 64;  // 4 or 2
    int lane = threadIdx.x & 63, wid = threadIdx.x >> 6;
    int node = blockIdx.x * (blockDim.x >> 6) + wid;
    if (node >= n) return;
    float dn = dinv[node];
    float acc[V];
    {
        const ushort* hn = h + (size_t)node * C + lane * V;
        if constexpr (V == 4) {
            ushort4 v = *reinterpret_cast<const ushort4*>(hn);
            acc[0] = dn * bf2f(v.x); acc[1] = dn * bf2f(v.y);
            acc[2] = dn * bf2f(v.z); acc[3] = dn * bf2f(v.w);
        } else {
            ushort2 v = *reinterpret_cast<const ushort2*>(hn);
            acc[0] = dn * bf2f(v.x); acc[1] = dn * bf2f(v.y);
        }
    }
    int j0 = offsets[node], j1 = offsets[node + 1];
    int j = j0;
    for (; j + 4 <= j1; j += 4) {
        int s0 = csr_src[j], s1 = csr_src[j + 1], s2 = csr_src[j + 2], s3 = csr_src[j + 3];
        float a0 = csr_a[j], a1 = csr_a[j + 1], a2 = csr_a[j + 2], a3 = csr_a[j + 3];
        if constexpr (V == 4) {
            ushort4 v0 = *reinterpret_cast<const ushort4*>(h + (size_t)s0 * C + lane * 4);
            ushort4 v1 = *reinterpret_cast<const ushort4*>(h + (size_t)s1 * C + lane * 4);
            ushort4 v2 = *reinterpret_cast<const ushort4*>(h + (size_t)s2 * C + lane * 4);
            ushort4 v3 = *reinterpret_cast<const ushort4*>(h + (size_t)s3 * C + lane * 4);
            acc[0] += a0 * bf2f(v0.x) + a1 * bf2f(v1.x) + a2 * bf2f(v2.x) + a3 * bf2f(v3.x);
            acc[1] += a0 * bf2f(v0.y) + a1 * bf2f(v1.y) + a2 * bf2f(v2.y) + a3 * bf2f(v3.y);
            acc[2] += a0 * bf2f(v0.z) + a1 * bf2f(v1.z) + a2 * bf2f(v2.z) + a3 * bf2f(v3.z);
            acc[3] += a0 * bf2f(v0.w) + a1 * bf2f(v1.w) + a2 * bf2f(v2.w) + a3 * bf2f(v3.w);
        } else {
            ushort2 v0 = *reinterpret_cast<const ushort2*>(h + (size_t)s0 * C + lane * 2);
            ushort2 v1 = *reinterpret_cast<const ushort2*>(h + (size_t)s1 * C + lane * 2);
            ushort2 v2 = *reinterpret_cast<const ushort2*>(h + (size_t)s2 * C + lane * 2);
            ushort2 v3 = *reinterpret_cast<const ushort2*>(h + (size_t)s3 * C + lane * 2);
            acc[0] += a0 * bf2f(v0.x) + a1 * bf2f(v1.x) + a2 * bf2f(v2.x) + a3 * bf2f(v3.x);
            acc[1] += a0 * bf2f(v0.y) + a1 * bf2f(v1.y) + a2 * bf2f(v2.y) + a3 * bf2f(v3.y);
        }
    }
    for (; j < j1; ++j) {
        int s = csr_src[j];
        float a = csr_a[j];
        const ushort* hs = h + (size_t)s * C + lane * V;
        if constexpr (V == 4) {
            ushort4 v = *reinterpret_cast<const ushort4*>(hs);
            acc[0] += a * bf2f(v.x); acc[1] += a * bf2f(v.y);
            acc[2] += a * bf2f(v.z); acc[3] += a * bf2f(v.w);
        } else {
            ushort2 v = *reinterpret_cast<const ushort2*>(hs);
            acc[0] += a * bf2f(v.x); acc[1] += a * bf2f(v.y);
        }
    }
    const float* bp = bias + lane * V;
    ushort* op = out + (size_t)node * C + lane * V;
    if constexpr (V == 4) {
        float o0 = acc[0] * dn + bp[0], o1 = acc[1] * dn + bp[1];
        float o2 = acc[2] * dn + bp[2], o3 = acc[3] * dn + bp[3];
        if (RELU) { o0 = fmaxf(o0, 0.f); o1 = fmaxf(o1, 0.f); o2 = fmaxf(o2, 0.f); o3 = fmaxf(o3, 0.f); }
        ushort4 o;
        o.x = f2bf(o0); o.y = f2bf(o1); o.z = f2bf(o2); o.w = f2bf(o3);
        *reinterpret_cast<ushort4*>(op) = o;
        if constexpr (FUSE) {
            float4 wms = *reinterpret_cast<const float4*>(W_m1 + lane * 4);
            float4 wmd = *reinterpret_cast<const float4*>(W_m1 + C + lane * 4);
            float ms = o0 * wms.x + o1 * wms.y + o2 * wms.z + o3 * wms.w;
            float md = o0 * wmd.x + o1 * wmd.y + o2 * wmd.z + o3 * wmd.w;
#pragma unroll
            for (int off = 32; off > 0; off >>= 1) {
                ms += __shfl_down(ms, off, 64);
                md += __shfl_down(md, off, 64);
            }
            if (lane == 0) { m_s[node] = ms; m_d[node] = md; }
        }
    } else {
        float o0 = acc[0] * dn + bp[0], o1 = acc[1] * dn + bp[1];
        if (RELU) { o0 = fmaxf(o0, 0.f); o1 = fmaxf(o1, 0.f); }
        ushort2 o;
        o.x = f2bf(o0); o.y = f2bf(o1);
        *reinterpret_cast<ushort2*>(op) = o;
    }
}

// ---------------- final pairwise classifier on y1 = out2 @ W_f1 ----------------
__global__ __launch_bounds__(256) void final_edge(const float* __restrict__ y1,
                                                  const int* __restrict__ ea,
                                                  const int* __restrict__ eb,
                                                  const float* __restrict__ b_f1,
                                                  const float* __restrict__ W_f2,
                                                  const float* __restrict__ b_f2,
                                                  float* __restrict__ out, int E) {
    int lane = threadIdx.x & 63, wid = threadIdx.x >> 6;
    int sub = lane >> 4, k4 = lane & 15;
    int wave = blockIdx.x * 4 + wid;
    int e = wave * 4 + sub;
    if (e >= E) return;
    float4 bf1 = *reinterpret_cast<const float4*>(b_f1 + k4 * 4);
    float4 wf2 = *reinterpret_cast<const float4*>(W_f2 + k4 * 4);
    int a = ea[e], b = eb[e];
    float4 va = *reinterpret_cast<const float4*>(y1 + (size_t)a * 64 + k4 * 4);
    float4 vb = *reinterpret_cast<const float4*>(y1 + (size_t)b * 64 + k4 * 4);
    float p = fmaxf(va.x - vb.x + bf1.x, 0.f) * wf2.x
            + fmaxf(va.y - vb.y + bf1.y, 0.f) * wf2.y
            + fmaxf(va.z - vb.z + bf1.z, 0.f) * wf2.z
            + fmaxf(va.w - vb.w + bf1.w, 0.f) * wf2.w;
    p += __shfl_xor(p, 1, 64);
    p += __shfl_xor(p, 2, 64);
    p += __shfl_xor(p, 4, 64);
    p += __shfl_xor(p, 8, 64);
    if (k4 == 0) out[e] = 1.f / (1.f + expf(-(p + b_f2[0])));
}

extern "C" void kernel_launch(void* const* d_in, const int* in_sizes, int n_in,
                              void* d_out, int out_size, void* d_ws, size_t ws_size,
                              hipStream_t stream) {
    const float* x      = (const float*)d_in[0];
    const float* coords = (const float*)d_in[1];
    const float* W_app  = (const float*)d_in[2];
    const float* b_app  = (const float*)d_in[3];
    const float* W_geom = (const float*)d_in[4];
    const float* b_geom = (const float*)d_in[5];
    const float* W_aff  = (const float*)d_in[6];
    const float* b_aff  = (const float*)d_in[7];
    const float* W_c1   = (const float*)d_in[8];
    const float* b_c1   = (const float*)d_in[9];
    const float* W_m1   = (const float*)d_in[10];
    const float* b_m1   = (const float*)d_in[11];
    const float* W_c2   = (const float*)d_in[12];
    const float* b_c2   = (const float*)d_in[13];
    const float* W_f1   = (const float*)d_in[14];
    const float* b_f1   = (const float*)d_in[15];
    const float* W_f2   = (const float*)d_in[16];
    const float* b_f2   = (const float*)d_in[17];
    const int*   e1     = (const int*)d_in[18];
    const int*   e2     = (const int*)d_in[19];
    float* out = (float*)d_out;

    const int N = NN;
    const int E = NE;
    const int MP = 50048;  // 391*128
    const int* src1 = e1;
    const int* dst1 = e1 + E;
    const int* e2a = e2;
    const int* e2b = e2 + E;

    char* ws = (char*)d_ws;
    size_t off = 0;
    auto alloc = [&](size_t bytes) -> void* {
        void* p = ws + off;
        off += (bytes + 255) & ~(size_t)255;
        return p;
    };
    float* app_s  = (float*)alloc((size_t)N * 4);
    float* app_d  = (float*)alloc((size_t)N * 4);
    float* geo_s  = (float*)alloc((size_t)N * 4);
    float* geo_d  = (float*)alloc((size_t)N * 4);
    float* m_s    = (float*)alloc((size_t)N * 4);
    float* m_d    = (float*)alloc((size_t)N * 4);
    float* dinv1  = (float*)alloc((size_t)N * 4);
    float* dinv2  = (float*)alloc((size_t)N * 4);
    int* cursor   = (int*)alloc((size_t)N * 4);
    int* offsets  = (int*)alloc((size_t)(N + 1) * 4);
    int* rank     = (int*)alloc((size_t)E * 4);
    int* csr_src  = (int*)alloc((size_t)E * 4);
    float* csr_ew = (float*)alloc((size_t)E * 4);  // phase1 weights, reused for phase2 w2
    float* csr_a  = (float*)alloc((size_t)E * 4);  // scaled coefficients (both phases)
    ushort* wc1T  = (ushort*)alloc((size_t)256 * 512 * 2);
    ushort* wc2T  = (ushort*)alloc((size_t)128 * 256 * 2);
    ushort* wf1T  = (ushort*)alloc((size_t)64 * 128 * 2);
    ushort* x_bf  = (ushort*)alloc((size_t)MP * 512 * 2);  // 51.25 MB (reused after gemm1)
    ushort* h_bf  = (ushort*)alloc((size_t)MP * 256 * 2);  // 25.62 MB (reused after conv1)
    // overlays:
    ushort* out1b = x_bf;                       // [MP,256] bf16 (x_bf dead after gemm1)
    ushort* h2b   = h_bf;                       // [N,128]  bf16 (h_bf dead after conv1)
    ushort* out2b = h_bf + (size_t)N * 128;     // [MP,128] bf16
    float*  y1    = (float*)out1b;              // [N,64]   f32  (out1b dead after gemm2)

    int gN = (N + 255) / 256;
    int gE = (E + 255) / 256;
    int gW = (N + 3) / 4;

    hipMemsetAsync(cursor, 0, (size_t)N * 4, stream);
    prep_x<<<gW, 256, 0, stream>>>(x, W_app, x_bf, app_s, app_d, N);
    cvt_wT<<<(512 * 256 + 255) / 256, 256, 0, stream>>>(W_c1, wc1T, 512, 256);
    cvt_wT<<<(256 * 128 + 255) / 256, 256, 0, stream>>>(W_c2, wc2T, 256, 128);
    cvt_wT<<<(128 * 64 + 255) / 256, 256, 0, stream>>>(W_f1, wf1T, 128, 64);
    geo_dot<<<gN, 256, 0, stream>>>(coords, W_geom, geo_s, geo_d, N);

    // CSR build: one atomic pass (rank+counts), scan, non-atomic place w/ inline edge weight
    scatter_rank<<<gE, 256, 0, stream>>>(dst1, cursor, rank, E);
    scan_kernel<<<1, 1024, 0, stream>>>(cursor, offsets, N);
    place_fused<<<gE, 256, 0, stream>>>(src1, dst1, rank, offsets, app_s, app_d, geo_s, geo_d,
                                        b_app, b_geom, W_aff, b_aff, csr_src, csr_ew, E);
    deg_dinv<<<gN, 256, 0, stream>>>(csr_ew, offsets, dinv1, N);
    scale_csr<<<gE, 256, 0, stream>>>(csr_src, dinv1, csr_ew, csr_a, E);

    // h_bf = bf16(x @ W_c1)
    mfma_gemm<2, 4, 4, true><<<dim3(MP / 128, 2), 256, 0, stream>>>(x_bf, wc1T, h_bf, N, 256, 512);
    // out1b = bf16(relu(agg(h_bf) + b_c1)) ; fused m_s/m_d dots
    conv_agg_bf<256, true, true><<<gW, 256, 0, stream>>>(h_bf, dinv1, csr_src, csr_a, offsets,
                                                         b_c1, out1b, W_m1, m_s, m_d, N);

    // phase-2 edge weights + dinv2, then scale (all non-atomic)
    phase2_rows<<<gN, 256, 0, stream>>>(csr_src, offsets, m_s, m_d, b_m1, csr_ew, dinv2, N);
    scale_csr<<<gE, 256, 0, stream>>>(csr_src, dinv2, csr_ew, csr_a, E);

    // h2b = bf16(out1b @ W_c2)
    mfma_gemm<2, 4, 4, true><<<dim3(MP / 128, 1), 256, 0, stream>>>(out1b, wc2T, h2b, N, 128, 256);
    // out2b = bf16(agg(h2b) + b_c2)
    conv_agg_bf<128, false, false><<<gW, 256, 0, stream>>>(h2b, dinv2, csr_src, csr_a, offsets,
                                                           b_c2, out2b, nullptr, nullptr, nullptr, N);

    // y1 = out2b @ W_f1 -> f32
    mfma_gemm<1, 2, 4, false><<<dim3(MP / 128, 1), 256, 0, stream>>>(out2b, wf1T, y1, N, 64, 128);

    // final pairwise classifier
    final_edge<<<E / 16, 256, 0, stream>>>(y1, e2a, e2b, b_f1, W_f2, b_f2, out, E);
}

// Round 5
// 312.816 us; speedup vs baseline: 3.2713x; 1.1177x over previous
//
#include <hip/hip_runtime.h>
#include <math.h>

#define NN 50000
#define NE 800000

typedef __attribute__((ext_vector_type(8))) short bf16x8;
typedef __attribute__((ext_vector_type(8))) unsigned short ushortx8;
typedef __attribute__((ext_vector_type(4))) float f32x4;

__device__ __forceinline__ float bf2f(ushort u) { return __uint_as_float(((unsigned)u) << 16); }
__device__ __forceinline__ ushort f2bf(float f) {
    unsigned b = __float_as_uint(f);
    return (ushort)((b + 0x7FFFu + ((b >> 16) & 1u)) >> 16);
}
__device__ __forceinline__ void load_lds16(const ushort* g, ushort* l) {
    __builtin_amdgcn_global_load_lds((const __attribute__((address_space(1))) unsigned int*)g,
                                     (__attribute__((address_space(3))) unsigned int*)l, 16, 0, 0);
}

// ---------------- fused x prep: x -> bf16, app_s/app_d dots ----------------
__global__ void prep_x(const float* __restrict__ x, const float* __restrict__ W_app,
                       ushort* __restrict__ x_bf, float* __restrict__ app_s,
                       float* __restrict__ app_d, int n) {
    int lane = threadIdx.x & 63, wid = threadIdx.x >> 6;
    int node = blockIdx.x * 4 + wid;
    if (node >= n) return;
    const float* xr = x + (size_t)node * 512 + lane * 8;
    float4 a = *reinterpret_cast<const float4*>(xr);
    float4 b = *reinterpret_cast<const float4*>(xr + 4);
    float4 ws0 = *reinterpret_cast<const float4*>(W_app + lane * 8);
    float4 ws1 = *reinterpret_cast<const float4*>(W_app + lane * 8 + 4);
    float4 wd0 = *reinterpret_cast<const float4*>(W_app + 512 + lane * 8);
    float4 wd1 = *reinterpret_cast<const float4*>(W_app + 512 + lane * 8 + 4);
    float ss = a.x * ws0.x + a.y * ws0.y + a.z * ws0.z + a.w * ws0.w
             + b.x * ws1.x + b.y * ws1.y + b.z * ws1.z + b.w * ws1.w;
    float dd = a.x * wd0.x + a.y * wd0.y + a.z * wd0.z + a.w * wd0.w
             + b.x * wd1.x + b.y * wd1.y + b.z * wd1.z + b.w * wd1.w;
    ushortx8 o;
    o.s0 = f2bf(a.x); o.s1 = f2bf(a.y); o.s2 = f2bf(a.z); o.s3 = f2bf(a.w);
    o.s4 = f2bf(b.x); o.s5 = f2bf(b.y); o.s6 = f2bf(b.z); o.s7 = f2bf(b.w);
    *reinterpret_cast<ushortx8*>(x_bf + (size_t)node * 512 + lane * 8) = o;
#pragma unroll
    for (int off = 32; off > 0; off >>= 1) {
        ss += __shfl_down(ss, off, 64);
        dd += __shfl_down(dd, off, 64);
    }
    if (lane == 0) { app_s[node] = ss; app_d[node] = dd; }
}

// WT[n*K+k] = bf16(W[k*N+n])
__global__ void cvt_wT(const float* __restrict__ W, ushort* __restrict__ WT, int K, int N) {
    int idx = blockIdx.x * blockDim.x + threadIdx.x;
    if (idx >= K * N) return;
    int k = idx / N, n = idx % N;
    WT[n * K + k] = f2bf(W[idx]);
}

// ---------------- geo dots ----------------
__global__ void geo_dot(const float* __restrict__ coords, const float* __restrict__ Wg,
                        float* __restrict__ geo_s, float* __restrict__ geo_d, int n) {
    int i = blockIdx.x * blockDim.x + threadIdx.x;
    if (i >= n) return;
    float4 c = *reinterpret_cast<const float4*>(coords + (size_t)i * 4);
    geo_s[i] = c.x * Wg[0] + c.y * Wg[1] + c.z * Wg[2] + c.w * Wg[3];
    geo_d[i] = c.x * Wg[4] + c.y * Wg[5] + c.z * Wg[6] + c.w * Wg[7];
}

// ---------------- CSR rank (the ONLY atomic pass: 800k) ----------------
__global__ void scatter_rank(const int* __restrict__ dst, int* __restrict__ cursor,
                             int* __restrict__ rank, int E) {
    int e = blockIdx.x * blockDim.x + threadIdx.x;
    if (e >= E) return;
    rank[e] = atomicAdd(&cursor[dst[e]], 1);
}

// ---------------- two-kernel scan: counts -> offsets ----------------
// scanA: per-block (1024 elems) totals
__global__ void scanA(const int* __restrict__ counts, int* __restrict__ btot, int n) {
    int b = blockIdx.x, tid = threadIdx.x;
    int lane = tid & 63, wid = tid >> 6;
    __shared__ int wsum[4];
    int i0 = b * 1024 + tid * 4;
    int s = 0;
#pragma unroll
    for (int k = 0; k < 4; ++k) { int i = i0 + k; if (i < n) s += counts[i]; }
#pragma unroll
    for (int off = 32; off > 0; off >>= 1) s += __shfl_down(s, off, 64);
    if (lane == 0) wsum[wid] = s;
    __syncthreads();
    if (tid == 0) btot[b] = wsum[0] + wsum[1] + wsum[2] + wsum[3];
}

// scanB: per-block full exclusive scan + base from btot
__global__ void scanB(const int* __restrict__ counts, const int* __restrict__ btot,
                      int* __restrict__ offsets, int n, int total) {
    int b = blockIdx.x, tid = threadIdx.x;
    int lane = tid & 63, wid = tid >> 6;
    __shared__ int base_sh;
    __shared__ int wpre[4];
    if (tid < 64) {
        int v = (tid < b) ? btot[tid] : 0;
#pragma unroll
        for (int off = 32; off > 0; off >>= 1) v += __shfl_down(v, off, 64);
        if (tid == 0) base_sh = v;
    }
    int i0 = b * 1024 + tid * 4;
    int v0 = 0, v1 = 0, v2 = 0, v3 = 0;
    if (i0 + 3 < n) {
        int4 t = *reinterpret_cast<const int4*>(counts + i0);
        v0 = t.x; v1 = t.y; v2 = t.z; v3 = t.w;
    } else {
        if (i0 + 0 < n) v0 = counts[i0 + 0];
        if (i0 + 1 < n) v1 = counts[i0 + 1];
        if (i0 + 2 < n) v2 = counts[i0 + 2];
        if (i0 + 3 < n) v3 = counts[i0 + 3];
    }
    int t = v0 + v1 + v2 + v3;
    int inc = t;
#pragma unroll
    for (int off = 1; off < 64; off <<= 1) {
        int u = __shfl_up(inc, off, 64);
        if (lane >= off) inc += u;
    }
    if (lane == 63) wpre[wid] = inc;
    __syncthreads();
    if (tid == 0) {
        int s = 0;
#pragma unroll
        for (int w = 0; w < 4; ++w) { int u = wpre[w]; wpre[w] = s; s += u; }
    }
    __syncthreads();
    int ex = base_sh + wpre[wid] + (inc - t);
    if (i0 + 3 < n) {
        int4 o;
        o.x = ex; o.y = ex + v0; o.z = ex + v0 + v1; o.w = ex + v0 + v1 + v2;
        *reinterpret_cast<int4*>(offsets + i0) = o;
    } else {
        if (i0 + 0 < n) offsets[i0 + 0] = ex;
        if (i0 + 1 < n) offsets[i0 + 1] = ex + v0;
        if (i0 + 2 < n) offsets[i0 + 2] = ex + v0 + v1;
        if (i0 + 3 < n) offsets[i0 + 3] = ex + v0 + v1 + v2;
    }
    if (b == 0 && tid == 0) offsets[n] = total;
}

// ---------------- place: edge weight inline, no atomics ----------------
__global__ void place_fused(const int* __restrict__ src, const int* __restrict__ dst,
                            const int* __restrict__ rank, const int* __restrict__ offsets,
                            const float* __restrict__ app_s, const float* __restrict__ app_d,
                            const float* __restrict__ geo_s, const float* __restrict__ geo_d,
                            const float* __restrict__ b_app, const float* __restrict__ b_geom,
                            const float* __restrict__ W_aff, const float* __restrict__ b_aff,
                            int* __restrict__ csr_src, float* __restrict__ csr_ew, int E) {
    int e = blockIdx.x * blockDim.x + threadIdx.x;
    if (e >= E) return;
    int s = src[e], d = dst[e];
    float x1 = fmaxf(app_s[s] + app_d[d] + b_app[0], 0.f);
    float x2 = fmaxf(geo_s[s] + geo_d[d] + b_geom[0], 0.f);
    float w = fmaxf(x1 * W_aff[0] + x2 * W_aff[1] + b_aff[0], 0.f);
    int pos = offsets[d] + rank[e];
    csr_src[pos] = s;
    csr_ew[pos] = w;
}

// ---------------- deg/dinv from row sums (no atomics) ----------------
__global__ void deg_dinv(const float* __restrict__ w, const int* __restrict__ offsets,
                         float* __restrict__ dinv, int n) {
    int i = blockIdx.x * blockDim.x + threadIdx.x;
    if (i >= n) return;
    int j0 = offsets[i], j1 = offsets[i + 1];
    float s = 1.f;  // self-loop weight
    for (int j = j0; j < j1; ++j) s += w[j];
    dinv[i] = rsqrtf(s);
}

// ---------------- phase 2: edge weights + dinv2 per row (no atomics) ----------------
__global__ void phase2_rows(const int* __restrict__ csr_src, const int* __restrict__ offsets,
                            const float* __restrict__ m_s, const float* __restrict__ m_d,
                            const float* __restrict__ b_m1,
                            float* __restrict__ w2, float* __restrict__ dinv2, int n) {
    int i = blockIdx.x * blockDim.x + threadIdx.x;
    if (i >= n) return;
    float md = m_d[i] + b_m1[0];
    int j0 = offsets[i], j1 = offsets[i + 1];
    float s = 1.f;
    for (int j = j0; j < j1; ++j) {
        float w = fmaxf(m_s[csr_src[j]] + md, 0.f);
        w2[j] = w;
        s += w;
    }
    dinv2[i] = rsqrtf(s);
}

// ---------------- MFMA bf16 GEMM: C[M,N] = A[M,K] * BT[N,K]^T ----------------
template <int WAVES_N, int MF, int NF, bool OUT_BF>
__global__ __launch_bounds__(256) void mfma_gemm(const ushort* __restrict__ A,
                                                 const ushort* __restrict__ BT,
                                                 void* __restrict__ Cout,
                                                 int M, int N, int K) {
    constexpr int WAVES_M = 4 / WAVES_N;
    constexpr int BM = WAVES_M * MF * 16;
    constexpr int BN = WAVES_N * NF * 16;
    constexpr int BK = 64;
    static_assert(BM == 128, "BM must be 128");
    __shared__ __align__(16) ushort As[BM * BK];
    __shared__ __align__(16) ushort Bs[BN * BK];
    const int tid = threadIdx.x;
    const int lane = tid & 63, wid = tid >> 6;
    const int wr = wid / WAVES_N, wc = wid % WAVES_N;
    const int m_blk = blockIdx.x * BM;
    const int n_blk = blockIdx.y * BN;

    const int slot = tid & 7;
    const int brow = tid >> 3;
    const int xslot = slot ^ (brow & 7);
    constexpr int ISS_A = BM / 32;
    constexpr int ISS_B = BN / 32;

    f32x4 acc[MF][NF];
#pragma unroll
    for (int i = 0; i < MF; ++i)
#pragma unroll
        for (int j = 0; j < NF; ++j) acc[i][j] = (f32x4){0.f, 0.f, 0.f, 0.f};

    const int frag_r_a = wr * (MF * 16) + (lane & 15);
    const int frag_r_b = wc * (NF * 16) + (lane & 15);
    const int frag_s = lane >> 4;

    const int nkt = K >> 6;
    for (int kt = 0; kt < nkt; ++kt) {
        const long kbase = (long)kt * 64;
#pragma unroll
        for (int i = 0; i < ISS_A; ++i) {
            int row = i * 32 + brow;
            const ushort* g = A + (long)(m_blk + row) * K + kbase + xslot * 8;
            load_lds16(g, As + i * 2048 + wid * 512);
        }
#pragma unroll
        for (int i = 0; i < ISS_B; ++i) {
            int row = i * 32 + brow;
            const ushort* g = BT + (long)(n_blk + row) * K + kbase + xslot * 8;
            load_lds16(g, Bs + i * 2048 + wid * 512);
        }
        asm volatile("s_waitcnt vmcnt(0)" ::: "memory");
        __syncthreads();
#pragma unroll
        for (int ks = 0; ks < 2; ++ks) {
            bf16x8 av[MF], bv[NF];
#pragma unroll
            for (int mf = 0; mf < MF; ++mf) {
                int r = frag_r_a + mf * 16;
                int s = ks * 4 + frag_s;
                av[mf] = *reinterpret_cast<const bf16x8*>(As + r * BK + ((s ^ (r & 7)) << 3));
            }
#pragma unroll
            for (int nf = 0; nf < NF; ++nf) {
                int r = frag_r_b + nf * 16;
                int s = ks * 4 + frag_s;
                bv[nf] = *reinterpret_cast<const bf16x8*>(Bs + r * BK + ((s ^ (r & 7)) << 3));
            }
#pragma unroll
            for (int mf = 0; mf < MF; ++mf)
#pragma unroll
                for (int nf = 0; nf < NF; ++nf)
                    acc[mf][nf] = __builtin_amdgcn_mfma_f32_16x16x32_bf16(av[mf], bv[nf], acc[mf][nf], 0, 0, 0);
        }
        __syncthreads();
    }
    const int col0 = n_blk + wc * NF * 16 + (lane & 15);
    const int row0 = m_blk + wr * MF * 16 + ((lane >> 4) << 2);
#pragma unroll
    for (int mf = 0; mf < MF; ++mf) {
#pragma unroll
        for (int r = 0; r < 4; ++r) {
            int row = row0 + mf * 16 + r;
            if (row < M) {
#pragma unroll
                for (int nf = 0; nf < NF; ++nf) {
                    if (OUT_BF)
                        ((ushort*)Cout)[(long)row * N + col0 + nf * 16] = f2bf(acc[mf][nf][r]);
                    else
                        ((float*)Cout)[(long)row * N + col0 + nf * 16] = acc[mf][nf][r];
                }
            }
        }
    }
}

// ---------------- GCN aggregation over bf16 features, fused dinv[src] scale ----------------
// out[node] = bf16( dn*(dn*h[n] + sum_j dinv[src_j]*w_j*h[src_j]) + bias )
template <int C, bool RELU, bool FUSE>
__global__ void conv_agg_bf(const ushort* __restrict__ h, const float* __restrict__ dinv,
                            const int* __restrict__ csr_src, const float* __restrict__ csr_w,
                            const int* __restrict__ offsets, const float* __restrict__ bias,
                            ushort* __restrict__ out,
                            const float* __restrict__ W_m1, float* __restrict__ m_s,
                            float* __restrict__ m_d, int n) {
    constexpr int V = C / 64;  // 4 or 2
    int lane = threadIdx.x & 63, wid = threadIdx.x >> 6;
    int node = blockIdx.x * (blockDim.x >> 6) + wid;
    if (node >= n) return;
    float dn = dinv[node];
    float acc[V];
    {
        const ushort* hn = h + (size_t)node * C + lane * V;
        if constexpr (V == 4) {
            ushort4 v = *reinterpret_cast<const ushort4*>(hn);
            acc[0] = dn * bf2f(v.x); acc[1] = dn * bf2f(v.y);
            acc[2] = dn * bf2f(v.z); acc[3] = dn * bf2f(v.w);
        } else {
            ushort2 v = *reinterpret_cast<const ushort2*>(hn);
            acc[0] = dn * bf2f(v.x); acc[1] = dn * bf2f(v.y);
        }
    }
    int j0 = offsets[node], j1 = offsets[node + 1];
    int j = j0;
    for (; j + 8 <= j1; j += 8) {
        int s[8]; float a[8];
#pragma unroll
        for (int q = 0; q < 8; ++q) s[q] = csr_src[j + q];
#pragma unroll
        for (int q = 0; q < 8; ++q) a[q] = dinv[s[q]] * csr_w[j + q];
        if constexpr (V == 4) {
            ushort4 v[8];
#pragma unroll
            for (int q = 0; q < 8; ++q)
                v[q] = *reinterpret_cast<const ushort4*>(h + (size_t)s[q] * C + lane * 4);
#pragma unroll
            for (int q = 0; q < 8; ++q) {
                acc[0] += a[q] * bf2f(v[q].x);
                acc[1] += a[q] * bf2f(v[q].y);
                acc[2] += a[q] * bf2f(v[q].z);
                acc[3] += a[q] * bf2f(v[q].w);
            }
        } else {
            ushort2 v[8];
#pragma unroll
            for (int q = 0; q < 8; ++q)
                v[q] = *reinterpret_cast<const ushort2*>(h + (size_t)s[q] * C + lane * 2);
#pragma unroll
            for (int q = 0; q < 8; ++q) {
                acc[0] += a[q] * bf2f(v[q].x);
                acc[1] += a[q] * bf2f(v[q].y);
            }
        }
    }
    for (; j < j1; ++j) {
        int s = csr_src[j];
        float a = dinv[s] * csr_w[j];
        const ushort* hs = h + (size_t)s * C + lane * V;
        if constexpr (V == 4) {
            ushort4 v = *reinterpret_cast<const ushort4*>(hs);
            acc[0] += a * bf2f(v.x); acc[1] += a * bf2f(v.y);
            acc[2] += a * bf2f(v.z); acc[3] += a * bf2f(v.w);
        } else {
            ushort2 v = *reinterpret_cast<const ushort2*>(hs);
            acc[0] += a * bf2f(v.x); acc[1] += a * bf2f(v.y);
        }
    }
    const float* bp = bias + lane * V;
    ushort* op = out + (size_t)node * C + lane * V;
    if constexpr (V == 4) {
        float o0 = acc[0] * dn + bp[0], o1 = acc[1] * dn + bp[1];
        float o2 = acc[2] * dn + bp[2], o3 = acc[3] * dn + bp[3];
        if (RELU) { o0 = fmaxf(o0, 0.f); o1 = fmaxf(o1, 0.f); o2 = fmaxf(o2, 0.f); o3 = fmaxf(o3, 0.f); }
        ushort4 o;
        o.x = f2bf(o0); o.y = f2bf(o1); o.z = f2bf(o2); o.w = f2bf(o3);
        *reinterpret_cast<ushort4*>(op) = o;
        if constexpr (FUSE) {
            float4 wms = *reinterpret_cast<const float4*>(W_m1 + lane * 4);
            float4 wmd = *reinterpret_cast<const float4*>(W_m1 + C + lane * 4);
            float ms = o0 * wms.x + o1 * wms.y + o2 * wms.z + o3 * wms.w;
            float md = o0 * wmd.x + o1 * wmd.y + o2 * wmd.z + o3 * wmd.w;
#pragma unroll
            for (int off = 32; off > 0; off >>= 1) {
                ms += __shfl_down(ms, off, 64);
                md += __shfl_down(md, off, 64);
            }
            if (lane == 0) { m_s[node] = ms; m_d[node] = md; }
        }
    } else {
        float o0 = acc[0] * dn + bp[0], o1 = acc[1] * dn + bp[1];
        if (RELU) { o0 = fmaxf(o0, 0.f); o1 = fmaxf(o1, 0.f); }
        ushort2 o;
        o.x = f2bf(o0); o.y = f2bf(o1);
        *reinterpret_cast<ushort2*>(op) = o;
    }
}

// ---------------- final pairwise classifier on bf16 y1 = out2 @ W_f1 ----------------
// 8 lanes per edge, 8 edges per wave.
__global__ __launch_bounds__(256) void final_edge(const ushort* __restrict__ y1,
                                                  const int* __restrict__ ea,
                                                  const int* __restrict__ eb,
                                                  const float* __restrict__ b_f1,
                                                  const float* __restrict__ W_f2,
                                                  const float* __restrict__ b_f2,
                                                  float* __restrict__ out, int E) {
    int lane = threadIdx.x & 63, wid = threadIdx.x >> 6;
    int sub = lane >> 3, k8 = lane & 7;
    int wave = blockIdx.x * 4 + wid;
    int e = wave * 8 + sub;
    if (e >= E) return;
    float4 bf1a = *reinterpret_cast<const float4*>(b_f1 + k8 * 8);
    float4 bf1b = *reinterpret_cast<const float4*>(b_f1 + k8 * 8 + 4);
    float4 wf2a = *reinterpret_cast<const float4*>(W_f2 + k8 * 8);
    float4 wf2b = *reinterpret_cast<const float4*>(W_f2 + k8 * 8 + 4);
    int a = ea[e], b = eb[e];
    ushortx8 va = *reinterpret_cast<const ushortx8*>(y1 + (size_t)a * 64 + k8 * 8);
    ushortx8 vb = *reinterpret_cast<const ushortx8*>(y1 + (size_t)b * 64 + k8 * 8);
    float p = fmaxf(bf2f(va.s0) - bf2f(vb.s0) + bf1a.x, 0.f) * wf2a.x
            + fmaxf(bf2f(va.s1) - bf2f(vb.s1) + bf1a.y, 0.f) * wf2a.y
            + fmaxf(bf2f(va.s2) - bf2f(vb.s2) + bf1a.z, 0.f) * wf2a.z
            + fmaxf(bf2f(va.s3) - bf2f(vb.s3) + bf1a.w, 0.f) * wf2a.w
            + fmaxf(bf2f(va.s4) - bf2f(vb.s4) + bf1b.x, 0.f) * wf2b.x
            + fmaxf(bf2f(va.s5) - bf2f(vb.s5) + bf1b.y, 0.f) * wf2b.y
            + fmaxf(bf2f(va.s6) - bf2f(vb.s6) + bf1b.z, 0.f) * wf2b.z
            + fmaxf(bf2f(va.s7) - bf2f(vb.s7) + bf1b.w, 0.f) * wf2b.w;
    p += __shfl_xor(p, 1, 64);
    p += __shfl_xor(p, 2, 64);
    p += __shfl_xor(p, 4, 64);
    if (k8 == 0) out[e] = 1.f / (1.f + expf(-(p + b_f2[0])));
}

extern "C" void kernel_launch(void* const* d_in, const int* in_sizes, int n_in,
                              void* d_out, int out_size, void* d_ws, size_t ws_size,
                              hipStream_t stream) {
    const float* x      = (const float*)d_in[0];
    const float* coords = (const float*)d_in[1];
    const float* W_app  = (const float*)d_in[2];
    const float* b_app  = (const float*)d_in[3];
    const float* W_geom = (const float*)d_in[4];
    const float* b_geom = (const float*)d_in[5];
    const float* W_aff  = (const float*)d_in[6];
    const float* b_aff  = (const float*)d_in[7];
    const float* W_c1   = (const float*)d_in[8];
    const float* b_c1   = (const float*)d_in[9];
    const float* W_m1   = (const float*)d_in[10];
    const float* b_m1   = (const float*)d_in[11];
    const float* W_c2   = (const float*)d_in[12];
    const float* b_c2   = (const float*)d_in[13];
    const float* W_f1   = (const float*)d_in[14];
    const float* b_f1   = (const float*)d_in[15];
    const float* W_f2   = (const float*)d_in[16];
    const float* b_f2   = (const float*)d_in[17];
    const int*   e1     = (const int*)d_in[18];
    const int*   e2     = (const int*)d_in[19];
    float* out = (float*)d_out;

    const int N = NN;
    const int E = NE;
    const int MP = 50048;  // 391*128
    const int* src1 = e1;
    const int* dst1 = e1 + E;
    const int* e2a = e2;
    const int* e2b = e2 + E;

    char* ws = (char*)d_ws;
    size_t off = 0;
    auto alloc = [&](size_t bytes) -> void* {
        void* p = ws + off;
        off += (bytes + 255) & ~(size_t)255;
        return p;
    };
    float* app_s  = (float*)alloc((size_t)N * 4);
    float* app_d  = (float*)alloc((size_t)N * 4);
    float* geo_s  = (float*)alloc((size_t)N * 4);
    float* geo_d  = (float*)alloc((size_t)N * 4);
    float* m_s    = (float*)alloc((size_t)N * 4);
    float* m_d    = (float*)alloc((size_t)N * 4);
    float* dinv1  = (float*)alloc((size_t)N * 4);
    float* dinv2  = (float*)alloc((size_t)N * 4);
    int* cursor   = (int*)alloc((size_t)N * 4);
    int* offsets  = (int*)alloc((size_t)(N + 1) * 4);
    int* btot     = (int*)alloc((size_t)64 * 4);
    int* rank     = (int*)alloc((size_t)E * 4);
    int* csr_src  = (int*)alloc((size_t)E * 4);
    float* csr_ew = (float*)alloc((size_t)E * 4);  // phase1 w, overwritten by phase2 w2
    ushort* wc1T  = (ushort*)alloc((size_t)256 * 512 * 2);
    ushort* wc2T  = (ushort*)alloc((size_t)128 * 256 * 2);
    ushort* wf1T  = (ushort*)alloc((size_t)64 * 128 * 2);
    ushort* x_bf  = (ushort*)alloc((size_t)MP * 512 * 2);  // 51.25 MB
    ushort* h_bf  = (ushort*)alloc((size_t)MP * 256 * 2);  // 25.62 MB
    // overlays:
    ushort* out1b = x_bf;                    // [MP,256] bf16 (x_bf dead after gemm1)
    ushort* h2b   = h_bf;                    // [N,128]  bf16 (h_bf dead after conv1)
    ushort* out2b = h_bf + (size_t)N * 128;  // [MP,128] bf16
    ushort* y1b   = x_bf;                    // [MP,64]  bf16 (out1b dead after gemm2)

    int gN = (N + 255) / 256;
    int gE = (E + 255) / 256;
    int gW = (N + 3) / 4;
    int nb = (N + 1023) / 1024;  // 49

    hipMemsetAsync(cursor, 0, (size_t)N * 4, stream);
    prep_x<<<gW, 256, 0, stream>>>(x, W_app, x_bf, app_s, app_d, N);
    cvt_wT<<<(512 * 256 + 255) / 256, 256, 0, stream>>>(W_c1, wc1T, 512, 256);
    cvt_wT<<<(256 * 128 + 255) / 256, 256, 0, stream>>>(W_c2, wc2T, 256, 128);
    cvt_wT<<<(128 * 64 + 255) / 256, 256, 0, stream>>>(W_f1, wf1T, 128, 64);
    geo_dot<<<gN, 256, 0, stream>>>(coords, W_geom, geo_s, geo_d, N);

    // CSR build: one atomic pass, two-kernel scan, non-atomic place w/ inline edge weight
    scatter_rank<<<gE, 256, 0, stream>>>(dst1, cursor, rank, E);
    scanA<<<nb, 256, 0, stream>>>(cursor, btot, N);
    scanB<<<nb, 256, 0, stream>>>(cursor, btot, offsets, N, E);
    place_fused<<<gE, 256, 0, stream>>>(src1, dst1, rank, offsets, app_s, app_d, geo_s, geo_d,
                                        b_app, b_geom, W_aff, b_aff, csr_src, csr_ew, E);
    deg_dinv<<<gN, 256, 0, stream>>>(csr_ew, offsets, dinv1, N);

    // h_bf = bf16(x @ W_c1)
    mfma_gemm<2, 4, 4, true><<<dim3(MP / 128, 2), 256, 0, stream>>>(x_bf, wc1T, h_bf, N, 256, 512);
    // out1b = bf16(relu(agg(h_bf) + b_c1)) ; fused dinv[src] scale + m_s/m_d dots
    conv_agg_bf<256, true, true><<<gW, 256, 0, stream>>>(h_bf, dinv1, csr_src, csr_ew, offsets,
                                                         b_c1, out1b, W_m1, m_s, m_d, N);

    // phase-2 edge weights + dinv2 (w2 overwrites csr_ew)
    phase2_rows<<<gN, 256, 0, stream>>>(csr_src, offsets, m_s, m_d, b_m1, csr_ew, dinv2, N);

    // h2b = bf16(out1b @ W_c2)
    mfma_gemm<2, 4, 4, true><<<dim3(MP / 128, 1), 256, 0, stream>>>(out1b, wc2T, h2b, N, 128, 256);
    // out2b = bf16(agg(h2b) + b_c2) ; fused dinv2[src] scale
    conv_agg_bf<128, false, false><<<gW, 256, 0, stream>>>(h2b, dinv2, csr_src, csr_ew, offsets,
                                                           b_c2, out2b, nullptr, nullptr, nullptr, N);

    // y1b = bf16(out2b @ W_f1)
    mfma_gemm<1, 2, 4, true><<<dim3(MP / 128, 1), 256, 0, stream>>>(out2b, wf1T, y1b, N, 64, 128);

    // final pairwise classifier (8 lanes/edge)
    final_edge<<<E / 32, 256, 0, stream>>>(y1b, e2a, e2b, b_f1, W_f2, b_f2, out, E);
}